// Round 1
// baseline (1965.150 us; speedup 1.0000x reference)
//
#include <hip/hip_runtime.h>
#include <cfloat>
#include <cstdint>
#include <cstddef>

// ---------------------------------------------------------------------------
// GPT-NeoX attention + H2O mask, MI355X. Rank-exact colsum path via fp16
// two-term splits and 3-product MFMA (error ~2^-22). R4: gemm3 rewritten as
// 256x256-tile 8-wave phased schedule with counted vmcnt (never drains to 0
// in the main loop), conflict-free xor swizzle, XCD-bijective block swizzle,
// setprio'd MFMA clusters. gemm1/attn unchanged this round.
// ---------------------------------------------------------------------------

#define S_LEN 2048
#define HID 4096
#define NHEAD 32
#define HSZ 128
#define HEAVY 204
#define RECENT 204
#define SEL_N 1844   // S - RECENT

typedef _Float16 f16;
typedef __attribute__((ext_vector_type(4))) _Float16 f16x4;
typedef __attribute__((ext_vector_type(8))) _Float16 f16x8;
typedef __attribute__((ext_vector_type(4))) float f32x4;

#define MFMA16 __builtin_amdgcn_mfma_f32_16x16x32_f16

__device__ __forceinline__ void async16(const void* g, void* l) {
  __builtin_amdgcn_global_load_lds(
      (const __attribute__((address_space(1))) unsigned int*)g,
      (__attribute__((address_space(3))) unsigned int*)l, 16, 0, 0);
}

// ---------------------------------------------------------------- converters
__global__ void cvt_split_h(const float* __restrict__ in, f16* __restrict__ o1,
                            f16* __restrict__ o2, int n4) {
  int i = blockIdx.x * 256 + threadIdx.x;
  if (i >= n4) return;
  float4 v = ((const float4*)in)[i];
  float vv[4] = {v.x, v.y, v.z, v.w};
  f16x4 a, b;
#pragma unroll
  for (int j = 0; j < 4; j++) {
    f16 h = (f16)vv[j];
    a[j] = h;
    b[j] = (f16)(vv[j] - (float)h);
  }
  ((f16x4*)o1)[i] = a;
  ((f16x4*)o2)[i] = b;
}

__global__ void cvt_wqk(const float* __restrict__ w, f16* __restrict__ o1,
                        f16* __restrict__ o2) {
  int i = blockIdx.x * 256 + threadIdx.x;   // over 8192*1024 float4s
  int col4 = i & 1023, r = i >> 10;
  int c = (r >> 8) * 384 + (r & 255);
  float4 v = ((const float4*)(w + (size_t)c * HID))[col4];
  float vv[4] = {v.x * 4096.f, v.y * 4096.f, v.z * 4096.f, v.w * 4096.f};
  f16x4 a, b;
#pragma unroll
  for (int j = 0; j < 4; j++) {
    f16 h = (f16)vv[j];
    a[j] = h;
    b[j] = (f16)(vv[j] - (float)h);
  }
  ((f16x4*)o1)[(size_t)r * 1024 + col4] = a;
  ((f16x4*)o2)[(size_t)r * 1024 + col4] = b;
}

__global__ void cvt_wv(const float* __restrict__ w, f16* __restrict__ o1) {
  int i = blockIdx.x * 256 + threadIdx.x;   // over 4096*1024
  int col4 = i & 1023, r = i >> 10;
  int c = (r >> 7) * 384 + 256 + (r & 127);
  float4 v = ((const float4*)(w + (size_t)c * HID))[col4];
  f16x4 a;
  a[0] = (f16)(v.x * 4096.f); a[1] = (f16)(v.y * 4096.f);
  a[2] = (f16)(v.z * 4096.f); a[3] = (f16)(v.w * 4096.f);
  ((f16x4*)o1)[(size_t)r * 1024 + col4] = a;
}

__global__ void cvt_wd(const float* __restrict__ w, f16* __restrict__ o1) {
  int i = blockIdx.x * 256 + threadIdx.x;
  float4 v = ((const float4*)w)[i];
  f16x4 a;
  a[0] = (f16)(v.x * 4096.f); a[1] = (f16)(v.y * 4096.f);
  a[2] = (f16)(v.z * 4096.f); a[3] = (f16)(v.w * 4096.f);
  ((f16x4*)o1)[i] = a;
}

__global__ void bias_perm(const float* __restrict__ qkvb, float* __restrict__ qkb,
                          float* __restrict__ vb) {
  int t = blockIdx.x * 256 + threadIdx.x;
  if (t < 8192) qkb[t] = qkvb[(t >> 8) * 384 + (t & 255)];
  else if (t < 12288) {
    int i = t - 8192;
    vb[i] = qkvb[(i >> 7) * 384 + 256 + (i & 127)];
  }
}

// cos/sin table: the only fp64 trig in the pipeline (32k evals, not 2M)
__global__ void rope_tab_kernel(const int* __restrict__ pos, float2* __restrict__ tab) {
  int idx = blockIdx.x * 256 + threadIdx.x;
  if (idx >= S_LEN * 16) return;
  int s = idx >> 4, i = idx & 15;
  float pf = (float)pow(10000.0, (double)i / 16.0);  // RN32 of true power
  float invf = 1.0f / pf;                             // = np 1.0/p
  float ph = (float)pos[s] * invf;                    // fp32 phase
  double pd = (double)ph;
  tab[idx] = make_float2((float)cos(pd), (float)sin(pd));
}

// ------------------------------------------------------- gemm3 (fp32-exact)
// C = ((A1+A2)@(B1+B2)^T)*descale + bias; drops A2*B2 (~2^-22).
// 256x256 tile, 8 waves (2x4), BK=32, double-buffered 128 KiB LDS.
// Per K-tile: 3 MFMA phases (a2*b1, a1*b2, a1*b1-in-reg) with counted
// vmcnt(4) before each of the two barriers -- prefetch for tile t+1 stays
// in flight across barriers; vmcnt never drains to 0 in the loop.
// LDS swizzle: linear DMA write with pre-swizzled global source so that
// chunk p of row r holds global k-chunk p ^ ((r>>1)&3); ds_read_b128 at
// chunk quad ^ ((cc>>1)&3) is then bank-conflict-free (8 consecutive lanes
// hit 8 distinct 4-bank groups).
__global__ __launch_bounds__(512, 2) void gemm3_f16(
    const f16* __restrict__ A1, const f16* __restrict__ A2,
    const f16* __restrict__ B1, const f16* __restrict__ B2,
    const float* __restrict__ bias, float* __restrict__ C,
    int M, int N, int K, float descale) {
  __shared__ __attribute__((aligned(16))) f16 A1s[2][256 * 32];
  __shared__ __attribute__((aligned(16))) f16 A2s[2][256 * 32];
  __shared__ __attribute__((aligned(16))) f16 B1s[2][256 * 32];
  __shared__ __attribute__((aligned(16))) f16 B2s[2][256 * 32];
  const int tid = threadIdx.x, wave = tid >> 6, lane = tid & 63;
  const int quad = lane >> 4, cc = lane & 15;
  const int wm = wave >> 2, wn = wave & 3;
  // XCD-bijective swizzle: XCD k owns M-panel k -> its 4 MB A-panel is
  // L2-resident; B streams from L3. (nwg == 256 == gridDim.x, nwg%8==0)
  const int nwgn = N >> 8;
  const int nwg = (M >> 8) * nwgn;
  int bid = blockIdx.x;
  int bidp = (bid & 7) * (nwg >> 3) + (bid >> 3);
  const int m0 = (bidp / nwgn) * 256, n0 = (bidp % nwgn) * 256;
  const int lrow = lane >> 2;
  const int lcs = ((lane & 3) ^ ((lane >> 3) & 3)) * 8;   // pre-swizzled src chunk
  const f16* A1g = A1 + (size_t)(m0 + wave * 16 + lrow) * K + lcs;
  const f16* A2g = A2 + (size_t)(m0 + wave * 16 + lrow) * K + lcs;
  const f16* B1g = B1 + (size_t)(n0 + wave * 16 + lrow) * K + lcs;
  const f16* B2g = B2 + (size_t)(n0 + wave * 16 + lrow) * K + lcs;
  const size_t HSTEP = (size_t)128 * K;
  const int ldst = wave * 16 * 32;   // this wave's 16-row slab (elem offset)
  f32x4 acc[8][4] = {};
  const int sA = (quad ^ ((cc >> 1) & 3)) * 8;   // swizzled read chunk
  // prologue: stage tile 0. Issue ORDER (B1,A2,A1,B2) is load-accounting ABI:
  // phase A waits vmcnt(4) for B1+A2, phase B waits vmcnt(4) for A1+B2.
  async16(B1g, &B1s[0][ldst]);
  async16(B1g + HSTEP, &B1s[0][ldst + 128 * 32]);
  async16(A2g, &A2s[0][ldst]);
  async16(A2g + HSTEP, &A2s[0][ldst + 128 * 32]);
  async16(A1g, &A1s[0][ldst]);
  async16(A1g + HSTEP, &A1s[0][ldst + 128 * 32]);
  async16(B2g, &B2s[0][ldst]);
  async16(B2g + HSTEP, &B2s[0][ldst + 128 * 32]);
  const int nt = K >> 5;
  f16x8 a1[8], b1[4], b2[4];
  for (int t = 0; t < nt; ++t) {
    const int buf = t & 1, nb = buf ^ 1;
    const int k1 = (t + 1 < nt) ? (t + 1) * 32 : 0;   // tail: harmless restage
    // ---- phase A: acc += a2*b1 ------------------------------------------
    asm volatile("s_waitcnt vmcnt(4)" ::: "memory");   // tile-t B1,A2 landed
    __builtin_amdgcn_s_barrier();
    __builtin_amdgcn_sched_barrier(0);
    async16(B1g + k1, &B1s[nb][ldst]);
    async16(B1g + HSTEP + k1, &B1s[nb][ldst + 128 * 32]);
    async16(A2g + k1, &A2s[nb][ldst]);
    async16(A2g + HSTEP + k1, &A2s[nb][ldst + 128 * 32]);
#pragma unroll
    for (int ni = 0; ni < 4; ni++)
      b1[ni] = *(const f16x8*)&B1s[buf][(wn * 64 + ni * 16 + cc) * 32 + sA];
    __builtin_amdgcn_s_setprio(1);
#pragma unroll
    for (int mi = 0; mi < 8; mi++) {
      f16x8 a2 = *(const f16x8*)&A2s[buf][(wm * 128 + mi * 16 + cc) * 32 + sA];
#pragma unroll
      for (int ni = 0; ni < 4; ni++)
        acc[mi][ni] = MFMA16(a2, b1[ni], acc[mi][ni], 0, 0, 0);
    }
    __builtin_amdgcn_s_setprio(0);
    // ---- phase B: acc += a1*b2 ------------------------------------------
    asm volatile("s_waitcnt vmcnt(4)" ::: "memory");   // tile-t A1,B2 landed
    __builtin_amdgcn_s_barrier();
    __builtin_amdgcn_sched_barrier(0);
    async16(A1g + k1, &A1s[nb][ldst]);
    async16(A1g + HSTEP + k1, &A1s[nb][ldst + 128 * 32]);
    async16(B2g + k1, &B2s[nb][ldst]);
    async16(B2g + HSTEP + k1, &B2s[nb][ldst + 128 * 32]);
#pragma unroll
    for (int ni = 0; ni < 4; ni++)
      b2[ni] = *(const f16x8*)&B2s[buf][(wn * 64 + ni * 16 + cc) * 32 + sA];
#pragma unroll
    for (int mi = 0; mi < 8; mi++)
      a1[mi] = *(const f16x8*)&A1s[buf][(wm * 128 + mi * 16 + cc) * 32 + sA];
    __builtin_amdgcn_s_setprio(1);
#pragma unroll
    for (int mi = 0; mi < 8; mi++)
#pragma unroll
      for (int ni = 0; ni < 4; ni++)
        acc[mi][ni] = MFMA16(a1[mi], b2[ni], acc[mi][ni], 0, 0, 0);
    __builtin_amdgcn_s_setprio(0);
    // ---- phase C: acc += a1*b1 (register-resident; no LDS, no barrier) ---
    __builtin_amdgcn_s_setprio(1);
#pragma unroll
    for (int mi = 0; mi < 8; mi++)
#pragma unroll
      for (int ni = 0; ni < 4; ni++)
        acc[mi][ni] = MFMA16(a1[mi], b1[ni], acc[mi][ni], 0, 0, 0);
    __builtin_amdgcn_s_setprio(0);
  }
  asm volatile("s_waitcnt vmcnt(0)" ::: "memory");   // drain tail prefetch
#pragma unroll
  for (int mi = 0; mi < 8; mi++) {
    int row = m0 + wm * 128 + mi * 16 + quad * 4;
#pragma unroll
    for (int ni = 0; ni < 4; ni++) {
      int col = n0 + wn * 64 + ni * 16 + cc;
      float bs = bias[col];
#pragma unroll
      for (int r = 0; r < 4; r++)
        C[(size_t)(row + r) * N + col] = acc[mi][ni][r] * descale + bs;
    }
  }
}

// -------------------------------------------------- gemm1 (loose-precision)
__global__ __launch_bounds__(256) void gemm1_f16(
    const f16* __restrict__ A, const f16* __restrict__ B,
    const float* __restrict__ bias, float* __restrict__ C,
    int M, int N, int K, float descale) {
  __shared__ __attribute__((aligned(16))) f16 As[128][32];
  __shared__ __attribute__((aligned(16))) f16 Bs[128][32];
  const int tid = threadIdx.x, wave = tid >> 6, lane = tid & 63;
  const int quad = lane >> 4, cc = lane & 15;
  const int m0 = blockIdx.y * 128, n0 = blockIdx.x * 128;
  const int wm = wave >> 1, wn = wave & 1;
  f32x4 acc[4][4] = {};
  const int lrow = lane >> 2;
  const int lcs = (((lane & 3) ^ (lrow & 3)) * 8);
  const int sA = (quad ^ (cc & 3)) * 8;
  const f16* Ag = A + (size_t)(m0 + wave * 32 + lrow) * K + lcs;
  const f16* Bg = B + (size_t)(n0 + wave * 32 + lrow) * K + lcs;
  for (int k0 = 0; k0 < K; k0 += 32) {
    __syncthreads();
    async16(Ag + k0, &As[wave * 32][0]);
    async16(Ag + (size_t)16 * K + k0, &As[wave * 32 + 16][0]);
    async16(Bg + k0, &Bs[wave * 32][0]);
    async16(Bg + (size_t)16 * K + k0, &Bs[wave * 32 + 16][0]);
    __syncthreads();
    f16x8 af[4], bfv[4];
#pragma unroll
    for (int mi = 0; mi < 4; mi++) af[mi] = *(const f16x8*)&As[wm * 64 + mi * 16 + cc][sA];
#pragma unroll
    for (int ni = 0; ni < 4; ni++) bfv[ni] = *(const f16x8*)&Bs[wn * 64 + ni * 16 + cc][sA];
#pragma unroll
    for (int mi = 0; mi < 4; mi++)
#pragma unroll
      for (int ni = 0; ni < 4; ni++)
        acc[mi][ni] = MFMA16(af[mi], bfv[ni], acc[mi][ni], 0, 0, 0);
  }
#pragma unroll
  for (int mi = 0; mi < 4; mi++) {
    int row = m0 + wm * 64 + mi * 16 + quad * 4;
#pragma unroll
    for (int ni = 0; ni < 4; ni++) {
      int col = n0 + wn * 64 + ni * 16 + cc;
      float bs = bias[col];
#pragma unroll
      for (int r = 0; r < 4; r++)
        C[(size_t)(row + r) * N + col] = acc[mi][ni][r] * descale + bs;
    }
  }
}

// ---------------------------------------------------------------- RoPE/split
__global__ void rope_split(const float* __restrict__ QKm, const float2* __restrict__ tab,
                           f16* __restrict__ Q1, f16* __restrict__ Q2,
                           f16* __restrict__ K1, f16* __restrict__ K2) {
  int idx = blockIdx.x * 256 + threadIdx.x;
  int d = idx & 127;
  int s = (idx >> 7) & 2047;
  int h = idx >> 18;
  const float* base = QKm + (size_t)s * 8192 + h * 256;
  float q = base[d], k = base[128 + d];
  if (d < 32) {
    int i = d & 15;
    float2 csn = tab[s * 16 + i];
    float cs = csn.x, sn = csn.y;
    int dp = (d < 16) ? d + 16 : d - 16;
    float qp = base[dp], kp = base[128 + dp];
    if (d < 16) { q = q * cs - qp * sn; k = k * cs - kp * sn; }
    else        { q = q * cs + qp * sn; k = k * cs + kp * sn; }
  }
  size_t o = (size_t)h * S_LEN * HSZ + (size_t)s * HSZ + d;
  f16 a = (f16)q; Q1[o] = a; Q2[o] = (f16)(q - (float)a);
  f16 b = (f16)k; K1[o] = b; K2[o] = (f16)(k - (float)b);
}

__global__ void v_transpose(const float* __restrict__ Vm, f16* __restrict__ Vt) {
  int h = blockIdx.y, s0 = blockIdx.x * 128;
  __shared__ f16 tile[128][130];
  int t = threadIdx.x;
#pragma unroll 4
  for (int it = 0; it < 64; ++it) {
    int lin = it * 256 + t;
    int d = lin & 127, sl = lin >> 7;
    tile[d][sl] = (f16)Vm[(size_t)(s0 + sl) * HID + h * HSZ + d];
  }
  __syncthreads();
#pragma unroll 4
  for (int it = 0; it < 64; ++it) {
    int lin = it * 256 + t;
    int sl = lin & 127, d = lin >> 7;
    Vt[(size_t)h * HSZ * S_LEN + (size_t)d * S_LEN + s0 + sl] = tile[d][sl];
  }
}

// -------------------------------------------------------------- flash pass 1
// Single-stage K1+K2 (64 KB LDS, 2 barriers/tile). Product order per sv:
// kc0..3 of (q2k1,q1k1), then kc0..3 of q1k2 — identical to pass2.
__global__ __launch_bounds__(256) void attn_pass1(
    const f16* __restrict__ Q1, const f16* __restrict__ Q2,
    const f16* __restrict__ K1g, const f16* __restrict__ K2g,
    const float* __restrict__ am, float* __restrict__ m_g, float* __restrict__ l_g) {
  const int bx = (int)gridDim.x - 1 - (int)blockIdx.x, h = blockIdx.y;
  const int tid = threadIdx.x, wave = tid >> 6, lane = tid & 63;
  const int quad = lane >> 4, cc = lane & 15;
  const int q0 = bx * 128;
  __shared__ __attribute__((aligned(16))) f16 K1s[4][128][32];
  __shared__ __attribute__((aligned(16))) f16 K2s[4][128][32];
  const f16* Qh1 = Q1 + (size_t)h * S_LEN * HSZ;
  const f16* Qh2 = Q2 + (size_t)h * S_LEN * HSZ;
  const f16* Kh1 = K1g + (size_t)h * S_LEN * HSZ;
  const f16* Kh2 = K2g + (size_t)h * S_LEN * HSZ;
  f16x8 qf1[2][4], qf2[2][4];
#pragma unroll
  for (int mi = 0; mi < 2; mi++)
#pragma unroll
    for (int kc = 0; kc < 4; kc++) {
      size_t off = (size_t)(q0 + wave * 32 + mi * 16 + cc) * HSZ + kc * 32 + quad * 8;
      qf1[mi][kc] = *(const f16x8*)(Qh1 + off);
      qf2[mi][kc] = *(const f16x8*)(Qh2 + off);
    }
  float rm[2][4], rl[2][4];
#pragma unroll
  for (int mi = 0; mi < 2; mi++)
#pragma unroll
    for (int r = 0; r < 4; r++) { rm[mi][r] = -1e30f; rl[mi][r] = 0.f; }
  const int lrow = lane >> 2;
  const int lcs = (((lane & 3) ^ (lrow & 3)) * 8);
  const int sA = (quad ^ (cc & 3)) * 8;
  for (int jt = 0; jt <= bx; ++jt) {
    int j0 = jt * 128;
    __syncthreads();
#pragma unroll
    for (int ii = 0; ii < 8; ++ii) {
      async16(Kh1 + (size_t)(j0 + ii * 16 + lrow) * HSZ + wave * 32 + lcs, &K1s[wave][ii * 16][0]);
      async16(Kh2 + (size_t)(j0 + ii * 16 + lrow) * HSZ + wave * 32 + lcs, &K2s[wave][ii * 16][0]);
    }
    __syncthreads();
    f32x4 sv[2][8] = {};
#pragma unroll
    for (int ni = 0; ni < 8; ni++)
#pragma unroll
      for (int kc = 0; kc < 4; kc++) {
        f16x8 b1 = *(const f16x8*)&K1s[kc][ni * 16 + cc][sA];
        sv[0][ni] = MFMA16(qf2[0][kc], b1, sv[0][ni], 0, 0, 0);
        sv[0][ni] = MFMA16(qf1[0][kc], b1, sv[0][ni], 0, 0, 0);
        sv[1][ni] = MFMA16(qf2[1][kc], b1, sv[1][ni], 0, 0, 0);
        sv[1][ni] = MFMA16(qf1[1][kc], b1, sv[1][ni], 0, 0, 0);
      }
#pragma unroll
    for (int ni = 0; ni < 8; ni++)
#pragma unroll
      for (int kc = 0; kc < 4; kc++) {
        f16x8 b2 = *(const f16x8*)&K2s[kc][ni * 16 + cc][sA];
        sv[0][ni] = MFMA16(qf1[0][kc], b2, sv[0][ni], 0, 0, 0);
        sv[1][ni] = MFMA16(qf1[1][kc], b2, sv[1][ni], 0, 0, 0);
      }
    bool diag = (jt == bx);
#pragma unroll
    for (int ni = 0; ni < 8; ni++) {
      int j = j0 + ni * 16 + cc;
      float a = am[j];
#pragma unroll
      for (int mi = 0; mi < 2; mi++)
#pragma unroll
        for (int r = 0; r < 4; r++) {
          int q = q0 + wave * 32 + mi * 16 + quad * 4 + r;
          float v = sv[mi][ni][r] / 11.313708498984761f + a;
          if (diag && j > q) v = -1e30f;
          sv[mi][ni][r] = v;
        }
    }
#pragma unroll
    for (int mi = 0; mi < 2; mi++)
#pragma unroll
      for (int r = 0; r < 4; r++) {
        float mx = sv[mi][0][r];
#pragma unroll
        for (int ni = 1; ni < 8; ni++) mx = fmaxf(mx, sv[mi][ni][r]);
#pragma unroll
        for (int o = 1; o < 16; o <<= 1) mx = fmaxf(mx, __shfl_xor(mx, o, 64));
        float nm = fmaxf(rm[mi][r], mx);
        float sum = 0.f;
#pragma unroll
        for (int ni = 0; ni < 8; ni++) sum += expf(sv[mi][ni][r] - nm);
#pragma unroll
        for (int o = 1; o < 16; o <<= 1) sum += __shfl_xor(sum, o, 64);
        rl[mi][r] = rl[mi][r] * expf(rm[mi][r] - nm) + sum;
        rm[mi][r] = nm;
      }
  }
  if (cc == 0) {
#pragma unroll
    for (int mi = 0; mi < 2; mi++)
#pragma unroll
      for (int r = 0; r < 4; r++) {
        int q = q0 + wave * 32 + mi * 16 + quad * 4 + r;
        m_g[h * S_LEN + q] = rm[mi][r];
        l_g[h * S_LEN + q] = rl[mi][r];
      }
  }
}

// -------------------------------------------------------------- flash pass 2
__global__ __launch_bounds__(256) void attn_pass2(
    const f16* __restrict__ Q1, const f16* __restrict__ Q2,
    const f16* __restrict__ K1g, const f16* __restrict__ K2g,
    const f16* __restrict__ Vt, const float* __restrict__ am,
    const float* __restrict__ m_g, const float* __restrict__ l_g,
    float* __restrict__ colsum, f16* __restrict__ attnb) {
  const int bx = (int)gridDim.x - 1 - (int)blockIdx.x, h = blockIdx.y;
  const int tid = threadIdx.x, wave = tid >> 6, lane = tid & 63;
  const int quad = lane >> 4, cc = lane & 15;
  const int q0 = bx * 128;
  __shared__ __attribute__((aligned(16))) f16 Kbuf[4][128][32];  // K1, then K2, then W
  __shared__ __attribute__((aligned(16))) f16 Vs[4][128][32];
  const f16* Qh1 = Q1 + (size_t)h * S_LEN * HSZ;
  const f16* Qh2 = Q2 + (size_t)h * S_LEN * HSZ;
  const f16* Kh1 = K1g + (size_t)h * S_LEN * HSZ;
  const f16* Kh2 = K2g + (size_t)h * S_LEN * HSZ;
  const f16* Vh = Vt + (size_t)h * HSZ * S_LEN;
  f16x8 qf1[2][4], qf2[2][4];
#pragma unroll
  for (int mi = 0; mi < 2; mi++)
#pragma unroll
    for (int kc = 0; kc < 4; kc++) {
      size_t off = (size_t)(q0 + wave * 32 + mi * 16 + cc) * HSZ + kc * 32 + quad * 8;
      qf1[mi][kc] = *(const f16x8*)(Qh1 + off);
      qf2[mi][kc] = *(const f16x8*)(Qh2 + off);
    }
  float rm[2][4], rl[2][4];
#pragma unroll
  for (int mi = 0; mi < 2; mi++)
#pragma unroll
    for (int r = 0; r < 4; r++) {
      int q = q0 + wave * 32 + mi * 16 + quad * 4 + r;
      rm[mi][r] = m_g[h * S_LEN + q];
      rl[mi][r] = l_g[h * S_LEN + q];
    }
  f32x4 oacc[2][8] = {};
  const int lrow = lane >> 2;
  const int lcs = (((lane & 3) ^ (lrow & 3)) * 8);
  const int sA = (quad ^ (cc & 3)) * 8;
  for (int jt = 0; jt <= bx; ++jt) {
    int j0 = jt * 128;
    __syncthreads();   // prior-iter PV reads done
#pragma unroll
    for (int ii = 0; ii < 8; ++ii) {
      async16(Kh1 + (size_t)(j0 + ii * 16 + lrow) * HSZ + wave * 32 + lcs, &Kbuf[wave][ii * 16][0]);
      async16(Vh + (size_t)(ii * 16 + lrow) * S_LEN + j0 + wave * 32 + lcs, &Vs[wave][ii * 16][0]);
    }
    __syncthreads();
    f32x4 sv[2][8] = {};
#pragma unroll
    for (int ni = 0; ni < 8; ni++)
#pragma unroll
      for (int kc = 0; kc < 4; kc++) {
        f16x8 b1 = *(const f16x8*)&Kbuf[kc][ni * 16 + cc][sA];
        sv[0][ni] = MFMA16(qf2[0][kc], b1, sv[0][ni], 0, 0, 0);
        sv[0][ni] = MFMA16(qf1[0][kc], b1, sv[0][ni], 0, 0, 0);
        sv[1][ni] = MFMA16(qf2[1][kc], b1, sv[1][ni], 0, 0, 0);
        sv[1][ni] = MFMA16(qf1[1][kc], b1, sv[1][ni], 0, 0, 0);
      }
    __syncthreads();   // all waves done reading K1
#pragma unroll
    for (int ii = 0; ii < 8; ++ii)
      async16(Kh2 + (size_t)(j0 + ii * 16 + lrow) * HSZ + wave * 32 + lcs, &Kbuf[wave][ii * 16][0]);
    __syncthreads();
#pragma unroll
    for (int ni = 0; ni < 8; ni++)
#pragma unroll
      for (int kc = 0; kc < 4; kc++) {
        f16x8 b2 = *(const f16x8*)&Kbuf[kc][ni * 16 + cc][sA];
        sv[0][ni] = MFMA16(qf1[0][kc], b2, sv[0][ni], 0, 0, 0);
        sv[1][ni] = MFMA16(qf1[1][kc], b2, sv[1][ni], 0, 0, 0);
      }
    bool diag = (jt == bx);
#pragma unroll
    for (int ni = 0; ni < 8; ni++) {
      int j = j0 + ni * 16 + cc;
      float a = am[j];
#pragma unroll
      for (int mi = 0; mi < 2; mi++)
#pragma unroll
        for (int r = 0; r < 4; r++) {
          int q = q0 + wave * 32 + mi * 16 + quad * 4 + r;
          float v = sv[mi][ni][r] / 11.313708498984761f + a;
          if (diag && j > q) v = -1e30f;
          sv[mi][ni][r] = expf(v - rm[mi][r]) / rl[mi][r];
        }
    }
#pragma unroll
    for (int ni = 0; ni < 8; ni++) {
      float p = 0.f;
#pragma unroll
      for (int mi = 0; mi < 2; mi++)
#pragma unroll
        for (int r = 0; r < 4; r++) p += sv[mi][ni][r];
      p += __shfl_xor(p, 16, 64);
      p += __shfl_xor(p, 32, 64);
      if (quad == 0) atomicAdd(&colsum[h * S_LEN + j0 + ni * 16 + cc], p);
    }
    __syncthreads();   // all waves done reading K2 before W overwrite
    // W element (q, j): row q_local, col ((jblk ^ (q&3))*8 + j%8); q&3 == r
#pragma unroll
    for (int ni = 0; ni < 8; ni++)
#pragma unroll
      for (int mi = 0; mi < 2; mi++)
#pragma unroll
        for (int r = 0; r < 4; r++) {
          int col = ((((ni & 1) * 2 + (cc >> 3)) ^ r) * 8) + (cc & 7);
          Kbuf[ni >> 1][wave * 32 + mi * 16 + quad * 4 + r][col] = (f16)sv[mi][ni][r];
        }
    // PV: each wave reads only its own 32 W rows
#pragma unroll
    for (int jc = 0; jc < 4; jc++) {
      f16x8 wf0 = *(const f16x8*)&Kbuf[jc][wave * 32 + cc][sA];
      f16x8 wf1 = *(const f16x8*)&Kbuf[jc][wave * 32 + 16 + cc][sA];
#pragma unroll
      for (int dn = 0; dn < 8; dn++) {
        f16x8 vf = *(const f16x8*)&Vs[jc][dn * 16 + cc][sA];
        oacc[0][dn] = MFMA16(wf0, vf, oacc[0][dn], 0, 0, 0);
        oacc[1][dn] = MFMA16(wf1, vf, oacc[1][dn], 0, 0, 0);
      }
    }
  }
#pragma unroll
  for (int mi = 0; mi < 2; mi++)
#pragma unroll
    for (int dn = 0; dn < 8; dn++)
#pragma unroll
      for (int r = 0; r < 4; r++) {
        int q = q0 + wave * 32 + mi * 16 + quad * 4 + r;
        attnb[(size_t)q * HID + h * HSZ + dn * 16 + cc] = (f16)oacc[mi][dn][r];
      }
}

// ------------------------------------------------------------- top-k -> mask
// Radix-select (4x8-bit, MSB first) of the 204th-largest key, then mark all
// strictly-greater + first k_rem equals by index (jax.lax.top_k tie rule).
__global__ void topk_mask_kernel(const float* __restrict__ colsum, float* __restrict__ outmask) {
  int h = blockIdx.x, t = threadIdx.x;
  __shared__ unsigned int keys[SEL_N];
  __shared__ int hist[256];
  __shared__ int sh_b, sh_acc, sh_gt;
  const float* cs = colsum + h * S_LEN;
  float* om = outmask + h * (S_LEN + 1);
  for (int i = t; i < SEL_N; i += 256) {
    unsigned int u = __float_as_uint(cs[i]);
    keys[i] = (u & 0x80000000u) ? ~u : (u | 0x80000000u);
  }
  for (int i = t; i < S_LEN + 1; i += 256) om[i] = (i >= S_LEN + 1 - RECENT) ? 1.f : 0.f;
  unsigned int pref = 0, pmask = 0;
  int k = HEAVY;
  for (int round = 0; round < 4; ++round) {
    int shift = 24 - 8 * round;
    if (t < 256) hist[t] = 0;
    __syncthreads();
    for (int i = t; i < SEL_N; i += 256) {
      unsigned int u = keys[i];
      if ((u & pmask) == pref) atomicAdd(&hist[(u >> shift) & 255], 1);
    }
    __syncthreads();
    if (t == 0) {
      int acc = 0, b = 255;
      for (; b > 0; --b) {
        int c = hist[b];
        if (acc + c >= k) break;
        acc += c;
      }
      sh_b = b; sh_acc = acc;
    }
    __syncthreads();
    k -= sh_acc;
    pref |= ((unsigned int)sh_b) << shift;
    pmask |= 0xFFu << shift;
    __syncthreads();
  }
  unsigned int T = pref;
  if (t == 0) sh_gt = 0;
  __syncthreads();
  for (int i = t; i < SEL_N; i += 256) {
    if (keys[i] > T) { om[i] = 1.0f; atomicAdd(&sh_gt, 1); }
  }
  __syncthreads();
  if (t == 0) {
    int krem = HEAVY - sh_gt;
    for (int i = 0; i < SEL_N && krem > 0; ++i)
      if (keys[i] == T) { om[i] = 1.0f; --krem; }
  }
}

// ------------------------------------------------------------------- launch
extern "C" void kernel_launch(void* const* d_in, const int* in_sizes, int n_in,
                              void* d_out, int out_size, void* d_ws, size_t ws_size,
                              hipStream_t stream) {
  const float* hs   = (const float*)d_in[0];
  const float* am   = (const float*)d_in[1];
  const int*   pos  = (const int*)d_in[2];
  const float* qkvw = (const float*)d_in[3];
  const float* qkvb = (const float*)d_in[4];
  const float* dw   = (const float*)d_in[5];
  const float* db   = (const float*)d_in[6];
  float* out = (float*)d_out;
  char* ws = (char*)d_ws;
  const size_t MB = 1048576;

  f16* H1 = (f16*)(ws);             // 16 MB
  f16* H2 = (f16*)(ws + 16 * MB);   // 16 MB
  f16* W1 = (f16*)(ws + 32 * MB);   // 64 MB  (dead after gemm3)
  f16* W2 = (f16*)(ws + 96 * MB);   // 64 MB  (dead after gemm3)
  f16* Wv = (f16*)(ws + 160 * MB);  // 32 MB
  f16* Wd = (f16*)(ws + 192 * MB);  // 32 MB
  float* QKm = (float*)(ws + 224 * MB);  // 64 MB
  float* Vm  = (float*)(ws + 288 * MB);  // 32 MB
  float* qkb = (float*)(ws + 320 * MB);
  float* vb  = (float*)(ws + 320 * MB + 65536);
  float* m_g = (float*)(ws + 321 * MB);
  float* l_g = (float*)(ws + 321 * MB + 262144);
  float* csum = (float*)(ws + 321 * MB + 524288);
  float2* tab = (float2*)(ws + 322 * MB);   // 256 KB; end ~322.25 MB
  // aliased into dead W1/W2 region after gemm3:
  f16* Q1 = (f16*)(ws + 32 * MB);
  f16* Q2 = (f16*)(ws + 48 * MB);
  f16* K1 = (f16*)(ws + 64 * MB);
  f16* K2 = (f16*)(ws + 80 * MB);
  f16* Vt = (f16*)(ws + 96 * MB);
  f16* attnb = (f16*)(ws + 112 * MB);

  rope_tab_kernel<<<128, 256, 0, stream>>>(pos, tab);
  cvt_split_h<<<8192, 256, 0, stream>>>(hs, H1, H2, 2097152);
  cvt_wqk<<<32768, 256, 0, stream>>>(qkvw, W1, W2);
  cvt_wv<<<16384, 256, 0, stream>>>(qkvw, Wv);
  cvt_wd<<<16384, 256, 0, stream>>>(dw, Wd);
  bias_perm<<<48, 256, 0, stream>>>(qkvb, qkb, vb);

  gemm3_f16<<<dim3(256), 512, 0, stream>>>(H1, H2, W1, W2, qkb, QKm,
                                           2048, 8192, 4096, 1.0f / 4096.0f);
  gemm1_f16<<<dim3(32, 16), 256, 0, stream>>>(H1, Wv, vb, Vm,
                                              2048, 4096, 4096, 1.0f / 4096.0f);
  rope_split<<<32768, 256, 0, stream>>>(QKm, tab, Q1, Q2, K1, K2);
  v_transpose<<<dim3(16, 32), 256, 0, stream>>>(Vm, Vt);

  hipMemsetAsync(csum, 0, NHEAD * S_LEN * sizeof(float), stream);
  attn_pass1<<<dim3(16, 32), 256, 0, stream>>>(Q1, Q2, K1, K2, am, m_g, l_g);
  attn_pass2<<<dim3(16, 32), 256, 0, stream>>>(Q1, Q2, K1, K2, Vt, am, m_g, l_g, csum, attnb);

  gemm1_f16<<<dim3(32, 16), 256, 0, stream>>>(attnb, Wd, db, out,
                                              2048, 4096, 4096, 1.0f / 4096.0f);
  topk_mask_kernel<<<32, 256, 0, stream>>>(csum, out + 8388608);
}

// Round 3
// 1891.868 us; speedup vs baseline: 1.0387x; 1.0387x over previous
//
#include <hip/hip_runtime.h>
#include <cfloat>
#include <cstdint>
#include <cstddef>

// ---------------------------------------------------------------------------
// GPT-NeoX attention + H2O mask, MI355X. Rank-exact colsum path via fp16
// two-term splits and 3-product MFMA (error ~2^-22). R5 (resubmit; R2 bench
// was an infra failure, kernel never ran): gemm3 keeps the round-0 geometry
// (128^2 tile, 256 thr, 3 blocks/CU, old swizzles, old grid) but replaces
// the 2-barrier drain-to-0 K-loop with a 6-slot LDS rotation:
// {B1,A2} double-buffered, {A1,B2} single-buffered, 3 barriers/K-tile, all
// waits vmcnt(4) (never 0 in the loop). Product order per accumulator is
// unchanged -> bit-identical numerics. Everything else == round-0 baseline.
// ---------------------------------------------------------------------------

#define S_LEN 2048
#define HID 4096
#define NHEAD 32
#define HSZ 128
#define HEAVY 204
#define RECENT 204
#define SEL_N 1844   // S - RECENT

typedef _Float16 f16;
typedef __attribute__((ext_vector_type(4))) _Float16 f16x4;
typedef __attribute__((ext_vector_type(8))) _Float16 f16x8;
typedef __attribute__((ext_vector_type(4))) float f32x4;

#define MFMA16 __builtin_amdgcn_mfma_f32_16x16x32_f16

__device__ __forceinline__ void async16(const void* g, void* l) {
  __builtin_amdgcn_global_load_lds(
      (const __attribute__((address_space(1))) unsigned int*)g,
      (__attribute__((address_space(3))) unsigned int*)l, 16, 0, 0);
}

// ---------------------------------------------------------------- converters
__global__ void cvt_split_h(const float* __restrict__ in, f16* __restrict__ o1,
                            f16* __restrict__ o2, int n4) {
  int i = blockIdx.x * 256 + threadIdx.x;
  if (i >= n4) return;
  float4 v = ((const float4*)in)[i];
  float vv[4] = {v.x, v.y, v.z, v.w};
  f16x4 a, b;
#pragma unroll
  for (int j = 0; j < 4; j++) {
    f16 h = (f16)vv[j];
    a[j] = h;
    b[j] = (f16)(vv[j] - (float)h);
  }
  ((f16x4*)o1)[i] = a;
  ((f16x4*)o2)[i] = b;
}

__global__ void cvt_wqk(const float* __restrict__ w, f16* __restrict__ o1,
                        f16* __restrict__ o2) {
  int i = blockIdx.x * 256 + threadIdx.x;   // over 8192*1024 float4s
  int col4 = i & 1023, r = i >> 10;
  int c = (r >> 8) * 384 + (r & 255);
  float4 v = ((const float4*)(w + (size_t)c * HID))[col4];
  float vv[4] = {v.x * 4096.f, v.y * 4096.f, v.z * 4096.f, v.w * 4096.f};
  f16x4 a, b;
#pragma unroll
  for (int j = 0; j < 4; j++) {
    f16 h = (f16)vv[j];
    a[j] = h;
    b[j] = (f16)(vv[j] - (float)h);
  }
  ((f16x4*)o1)[(size_t)r * 1024 + col4] = a;
  ((f16x4*)o2)[(size_t)r * 1024 + col4] = b;
}

__global__ void cvt_wv(const float* __restrict__ w, f16* __restrict__ o1) {
  int i = blockIdx.x * 256 + threadIdx.x;   // over 4096*1024
  int col4 = i & 1023, r = i >> 10;
  int c = (r >> 7) * 384 + 256 + (r & 127);
  float4 v = ((const float4*)(w + (size_t)c * HID))[col4];
  f16x4 a;
  a[0] = (f16)(v.x * 4096.f); a[1] = (f16)(v.y * 4096.f);
  a[2] = (f16)(v.z * 4096.f); a[3] = (f16)(v.w * 4096.f);
  ((f16x4*)o1)[(size_t)r * 1024 + col4] = a;
}

__global__ void cvt_wd(const float* __restrict__ w, f16* __restrict__ o1) {
  int i = blockIdx.x * 256 + threadIdx.x;
  float4 v = ((const float4*)w)[i];
  f16x4 a;
  a[0] = (f16)(v.x * 4096.f); a[1] = (f16)(v.y * 4096.f);
  a[2] = (f16)(v.z * 4096.f); a[3] = (f16)(v.w * 4096.f);
  ((f16x4*)o1)[i] = a;
}

__global__ void bias_perm(const float* __restrict__ qkvb, float* __restrict__ qkb,
                          float* __restrict__ vb) {
  int t = blockIdx.x * 256 + threadIdx.x;
  if (t < 8192) qkb[t] = qkvb[(t >> 8) * 384 + (t & 255)];
  else if (t < 12288) {
    int i = t - 8192;
    vb[i] = qkvb[(i >> 7) * 384 + 256 + (i & 127)];
  }
}

// cos/sin table: the only fp64 trig in the pipeline (32k evals, not 2M)
__global__ void rope_tab_kernel(const int* __restrict__ pos, float2* __restrict__ tab) {
  int idx = blockIdx.x * 256 + threadIdx.x;
  if (idx >= S_LEN * 16) return;
  int s = idx >> 4, i = idx & 15;
  float pf = (float)pow(10000.0, (double)i / 16.0);  // RN32 of true power
  float invf = 1.0f / pf;                             // = np 1.0/p
  float ph = (float)pos[s] * invf;                    // fp32 phase
  double pd = (double)ph;
  tab[idx] = make_float2((float)cos(pd), (float)sin(pd));
}

// ------------------------------------------------------- gemm3 (fp32-exact)
// C = ((A1+A2)@(B1+B2)^T)*descale + bias; drops A2*B2 (~2^-22).
// Round-0 geometry; 6-slot counted-vmcnt schedule:
//   slots: B1s[2], A2s[2] (dbuf, read in phase A), A1s, B2s (single, phase B).
//   per K-tile: [vmcnt(4); bar A; issue B1/A2(t+1); phase A mfma(a2,b1)]
//               [vmcnt(4); bar B; phase B mfma(a1,b2)]
//               [bar C; issue A1/B2(t+1); phase C mfma(a1,b1) from regs]
//   per-wave vmcnt groups of 4; 8 outstanding steady-state; never drains.
//   vmcnt-before-barrier gives the cross-wave "DMA landed" guarantee.
//   No other in-loop VMEM ops -> counts are exact (bias/C are post-loop,
//   post-drain).
__global__ __launch_bounds__(256) void gemm3_f16(
    const f16* __restrict__ A1, const f16* __restrict__ A2,
    const f16* __restrict__ B1, const f16* __restrict__ B2,
    const float* __restrict__ bias, float* __restrict__ C,
    int M, int N, int K, float descale) {
  __shared__ __attribute__((aligned(16))) f16 B1s[2][128][32];
  __shared__ __attribute__((aligned(16))) f16 A2s[2][128][32];
  __shared__ __attribute__((aligned(16))) f16 A1s[128][32];
  __shared__ __attribute__((aligned(16))) f16 B2s[128][32];
  const int tid = threadIdx.x, wave = tid >> 6, lane = tid & 63;
  const int quad = lane >> 4, cc = lane & 15;
  const int m0 = blockIdx.y * 128, n0 = blockIdx.x * 128;
  const int wm = wave >> 1, wn = wave & 1;
  f32x4 acc[4][4] = {};
  const int lrow = lane >> 2;
  const int lcs = (((lane & 3) ^ (lrow & 3)) * 8);   // pre-swizzled src chunk
  const int sA = (quad ^ (cc & 3)) * 8;              // swizzled read seg
  const f16* A1g = A1 + (size_t)(m0 + wave * 32 + lrow) * K + lcs;
  const f16* A2g = A2 + (size_t)(m0 + wave * 32 + lrow) * K + lcs;
  const f16* B1g = B1 + (size_t)(n0 + wave * 32 + lrow) * K + lcs;
  const f16* B2g = B2 + (size_t)(n0 + wave * 32 + lrow) * K + lcs;
  const size_t RSTEP = (size_t)16 * K;
  const int nt = K >> 5;
  // prologue: group1(t=0) = {B1,A2}, then group2(t=0) = {A1,B2}
  async16(B1g, &B1s[0][wave * 32][0]);
  async16(B1g + RSTEP, &B1s[0][wave * 32 + 16][0]);
  async16(A2g, &A2s[0][wave * 32][0]);
  async16(A2g + RSTEP, &A2s[0][wave * 32 + 16][0]);
  async16(A1g, &A1s[wave * 32][0]);
  async16(A1g + RSTEP, &A1s[wave * 32 + 16][0]);
  async16(B2g, &B2s[wave * 32][0]);
  async16(B2g + RSTEP, &B2s[wave * 32 + 16][0]);
  f16x8 a1[4], b1[4];
  for (int t = 0; t < nt; ++t) {
    const int buf = t & 1, nb = buf ^ 1;
    const int kn = (t + 1 < nt) ? (t + 1) * 32 : 0;  // tail: harmless restage
    // ---- barrier A: need B1[t],A2[t] (oldest 4 of 8 outstanding) ---------
    asm volatile("s_waitcnt vmcnt(4)" ::: "memory");
    __builtin_amdgcn_s_barrier();
    __builtin_amdgcn_sched_barrier(0);
    async16(B1g + kn, &B1s[nb][wave * 32][0]);
    async16(B1g + RSTEP + kn, &B1s[nb][wave * 32 + 16][0]);
    async16(A2g + kn, &A2s[nb][wave * 32][0]);
    async16(A2g + RSTEP + kn, &A2s[nb][wave * 32 + 16][0]);
    // ---- phase A: acc += a2*b1 -------------------------------------------
#pragma unroll
    for (int ni = 0; ni < 4; ni++)
      b1[ni] = *(const f16x8*)&B1s[buf][wn * 64 + ni * 16 + cc][sA];
    __builtin_amdgcn_s_setprio(1);
#pragma unroll
    for (int mi = 0; mi < 4; mi++) {
      f16x8 a2 = *(const f16x8*)&A2s[buf][wm * 64 + mi * 16 + cc][sA];
#pragma unroll
      for (int ni = 0; ni < 4; ni++)
        acc[mi][ni] = MFMA16(a2, b1[ni], acc[mi][ni], 0, 0, 0);
    }
    __builtin_amdgcn_s_setprio(0);
    // ---- barrier B: need A1[t],B2[t] (oldest 4; B1/A2[t+1] younger) ------
    asm volatile("s_waitcnt vmcnt(4)" ::: "memory");
    __builtin_amdgcn_s_barrier();
    __builtin_amdgcn_sched_barrier(0);
    // ---- phase B: acc += a1*b2 -------------------------------------------
#pragma unroll
    for (int mi = 0; mi < 4; mi++)
      a1[mi] = *(const f16x8*)&A1s[wm * 64 + mi * 16 + cc][sA];
    __builtin_amdgcn_s_setprio(1);
#pragma unroll
    for (int ni = 0; ni < 4; ni++) {
      f16x8 b2 = *(const f16x8*)&B2s[wn * 64 + ni * 16 + cc][sA];
#pragma unroll
      for (int mi = 0; mi < 4; mi++)
        acc[mi][ni] = MFMA16(a1[mi], b2, acc[mi][ni], 0, 0, 0);
    }
    __builtin_amdgcn_s_setprio(0);
    // ---- barrier C: all waves done reading A1s/B2s -> safe to overwrite --
    __builtin_amdgcn_s_barrier();
    __builtin_amdgcn_sched_barrier(0);
    async16(A1g + kn, &A1s[wave * 32][0]);
    async16(A1g + RSTEP + kn, &A1s[wave * 32 + 16][0]);
    async16(B2g + kn, &B2s[wave * 32][0]);
    async16(B2g + RSTEP + kn, &B2s[wave * 32 + 16][0]);
    // ---- phase C: acc += a1*b1 (register-resident) -----------------------
    __builtin_amdgcn_s_setprio(1);
#pragma unroll
    for (int mi = 0; mi < 4; mi++)
#pragma unroll
      for (int ni = 0; ni < 4; ni++)
        acc[mi][ni] = MFMA16(a1[mi], b1[ni], acc[mi][ni], 0, 0, 0);
    __builtin_amdgcn_s_setprio(0);
  }
  asm volatile("s_waitcnt vmcnt(0)" ::: "memory");   // drain tail restage
#pragma unroll
  for (int mi = 0; mi < 4; mi++) {
    int row = m0 + wm * 64 + mi * 16 + quad * 4;
#pragma unroll
    for (int ni = 0; ni < 4; ni++) {
      int col = n0 + wn * 64 + ni * 16 + cc;
      float bs = bias[col];
#pragma unroll
      for (int r = 0; r < 4; r++)
        C[(size_t)(row + r) * N + col] = acc[mi][ni][r] * descale + bs;
    }
  }
}

// -------------------------------------------------- gemm1 (loose-precision)
__global__ __launch_bounds__(256) void gemm1_f16(
    const f16* __restrict__ A, const f16* __restrict__ B,
    const float* __restrict__ bias, float* __restrict__ C,
    int M, int N, int K, float descale) {
  __shared__ __attribute__((aligned(16))) f16 As[128][32];
  __shared__ __attribute__((aligned(16))) f16 Bs[128][32];
  const int tid = threadIdx.x, wave = tid >> 6, lane = tid & 63;
  const int quad = lane >> 4, cc = lane & 15;
  const int m0 = blockIdx.y * 128, n0 = blockIdx.x * 128;
  const int wm = wave >> 1, wn = wave & 1;
  f32x4 acc[4][4] = {};
  const int lrow = lane >> 2;
  const int lcs = (((lane & 3) ^ (lrow & 3)) * 8);
  const int sA = (quad ^ (cc & 3)) * 8;
  const f16* Ag = A + (size_t)(m0 + wave * 32 + lrow) * K + lcs;
  const f16* Bg = B + (size_t)(n0 + wave * 32 + lrow) * K + lcs;
  for (int k0 = 0; k0 < K; k0 += 32) {
    __syncthreads();
    async16(Ag + k0, &As[wave * 32][0]);
    async16(Ag + (size_t)16 * K + k0, &As[wave * 32 + 16][0]);
    async16(Bg + k0, &Bs[wave * 32][0]);
    async16(Bg + (size_t)16 * K + k0, &Bs[wave * 32 + 16][0]);
    __syncthreads();
    f16x8 af[4], bfv[4];
#pragma unroll
    for (int mi = 0; mi < 4; mi++) af[mi] = *(const f16x8*)&As[wm * 64 + mi * 16 + cc][sA];
#pragma unroll
    for (int ni = 0; ni < 4; ni++) bfv[ni] = *(const f16x8*)&Bs[wn * 64 + ni * 16 + cc][sA];
#pragma unroll
    for (int mi = 0; mi < 4; mi++)
#pragma unroll
      for (int ni = 0; ni < 4; ni++)
        acc[mi][ni] = MFMA16(af[mi], bfv[ni], acc[mi][ni], 0, 0, 0);
  }
#pragma unroll
  for (int mi = 0; mi < 4; mi++) {
    int row = m0 + wm * 64 + mi * 16 + quad * 4;
#pragma unroll
    for (int ni = 0; ni < 4; ni++) {
      int col = n0 + wn * 64 + ni * 16 + cc;
      float bs = bias[col];
#pragma unroll
      for (int r = 0; r < 4; r++)
        C[(size_t)(row + r) * N + col] = acc[mi][ni][r] * descale + bs;
    }
  }
}

// ---------------------------------------------------------------- RoPE/split
__global__ void rope_split(const float* __restrict__ QKm, const float2* __restrict__ tab,
                           f16* __restrict__ Q1, f16* __restrict__ Q2,
                           f16* __restrict__ K1, f16* __restrict__ K2) {
  int idx = blockIdx.x * 256 + threadIdx.x;
  int d = idx & 127;
  int s = (idx >> 7) & 2047;
  int h = idx >> 18;
  const float* base = QKm + (size_t)s * 8192 + h * 256;
  float q = base[d], k = base[128 + d];
  if (d < 32) {
    int i = d & 15;
    float2 csn = tab[s * 16 + i];
    float cs = csn.x, sn = csn.y;
    int dp = (d < 16) ? d + 16 : d - 16;
    float qp = base[dp], kp = base[128 + dp];
    if (d < 16) { q = q * cs - qp * sn; k = k * cs - kp * sn; }
    else        { q = q * cs + qp * sn; k = k * cs + kp * sn; }
  }
  size_t o = (size_t)h * S_LEN * HSZ + (size_t)s * HSZ + d;
  f16 a = (f16)q; Q1[o] = a; Q2[o] = (f16)(q - (float)a);
  f16 b = (f16)k; K1[o] = b; K2[o] = (f16)(k - (float)b);
}

__global__ void v_transpose(const float* __restrict__ Vm, f16* __restrict__ Vt) {
  int h = blockIdx.y, s0 = blockIdx.x * 128;
  __shared__ f16 tile[128][130];
  int t = threadIdx.x;
#pragma unroll 4
  for (int it = 0; it < 64; ++it) {
    int lin = it * 256 + t;
    int d = lin & 127, sl = lin >> 7;
    tile[d][sl] = (f16)Vm[(size_t)(s0 + sl) * HID + h * HSZ + d];
  }
  __syncthreads();
#pragma unroll 4
  for (int it = 0; it < 64; ++it) {
    int lin = it * 256 + t;
    int sl = lin & 127, d = lin >> 7;
    Vt[(size_t)h * HSZ * S_LEN + (size_t)d * S_LEN + s0 + sl] = tile[d][sl];
  }
}

// -------------------------------------------------------------- flash pass 1
// Single-stage K1+K2 (64 KB LDS, 2 barriers/tile). Product order per sv:
// kc0..3 of (q2k1,q1k1), then kc0..3 of q1k2 — identical to pass2.
__global__ __launch_bounds__(256) void attn_pass1(
    const f16* __restrict__ Q1, const f16* __restrict__ Q2,
    const f16* __restrict__ K1g, const f16* __restrict__ K2g,
    const float* __restrict__ am, float* __restrict__ m_g, float* __restrict__ l_g) {
  const int bx = (int)gridDim.x - 1 - (int)blockIdx.x, h = blockIdx.y;
  const int tid = threadIdx.x, wave = tid >> 6, lane = tid & 63;
  const int quad = lane >> 4, cc = lane & 15;
  const int q0 = bx * 128;
  __shared__ __attribute__((aligned(16))) f16 K1s[4][128][32];
  __shared__ __attribute__((aligned(16))) f16 K2s[4][128][32];
  const f16* Qh1 = Q1 + (size_t)h * S_LEN * HSZ;
  const f16* Qh2 = Q2 + (size_t)h * S_LEN * HSZ;
  const f16* Kh1 = K1g + (size_t)h * S_LEN * HSZ;
  const f16* Kh2 = K2g + (size_t)h * S_LEN * HSZ;
  f16x8 qf1[2][4], qf2[2][4];
#pragma unroll
  for (int mi = 0; mi < 2; mi++)
#pragma unroll
    for (int kc = 0; kc < 4; kc++) {
      size_t off = (size_t)(q0 + wave * 32 + mi * 16 + cc) * HSZ + kc * 32 + quad * 8;
      qf1[mi][kc] = *(const f16x8*)(Qh1 + off);
      qf2[mi][kc] = *(const f16x8*)(Qh2 + off);
    }
  float rm[2][4], rl[2][4];
#pragma unroll
  for (int mi = 0; mi < 2; mi++)
#pragma unroll
    for (int r = 0; r < 4; r++) { rm[mi][r] = -1e30f; rl[mi][r] = 0.f; }
  const int lrow = lane >> 2;
  const int lcs = (((lane & 3) ^ (lrow & 3)) * 8);
  const int sA = (quad ^ (cc & 3)) * 8;
  for (int jt = 0; jt <= bx; ++jt) {
    int j0 = jt * 128;
    __syncthreads();
#pragma unroll
    for (int ii = 0; ii < 8; ++ii) {
      async16(Kh1 + (size_t)(j0 + ii * 16 + lrow) * HSZ + wave * 32 + lcs, &K1s[wave][ii * 16][0]);
      async16(Kh2 + (size_t)(j0 + ii * 16 + lrow) * HSZ + wave * 32 + lcs, &K2s[wave][ii * 16][0]);
    }
    __syncthreads();
    f32x4 sv[2][8] = {};
#pragma unroll
    for (int ni = 0; ni < 8; ni++)
#pragma unroll
      for (int kc = 0; kc < 4; kc++) {
        f16x8 b1 = *(const f16x8*)&K1s[kc][ni * 16 + cc][sA];
        sv[0][ni] = MFMA16(qf2[0][kc], b1, sv[0][ni], 0, 0, 0);
        sv[0][ni] = MFMA16(qf1[0][kc], b1, sv[0][ni], 0, 0, 0);
        sv[1][ni] = MFMA16(qf2[1][kc], b1, sv[1][ni], 0, 0, 0);
        sv[1][ni] = MFMA16(qf1[1][kc], b1, sv[1][ni], 0, 0, 0);
      }
#pragma unroll
    for (int ni = 0; ni < 8; ni++)
#pragma unroll
      for (int kc = 0; kc < 4; kc++) {
        f16x8 b2 = *(const f16x8*)&K2s[kc][ni * 16 + cc][sA];
        sv[0][ni] = MFMA16(qf1[0][kc], b2, sv[0][ni], 0, 0, 0);
        sv[1][ni] = MFMA16(qf1[1][kc], b2, sv[1][ni], 0, 0, 0);
      }
    bool diag = (jt == bx);
#pragma unroll
    for (int ni = 0; ni < 8; ni++) {
      int j = j0 + ni * 16 + cc;
      float a = am[j];
#pragma unroll
      for (int mi = 0; mi < 2; mi++)
#pragma unroll
        for (int r = 0; r < 4; r++) {
          int q = q0 + wave * 32 + mi * 16 + quad * 4 + r;
          float v = sv[mi][ni][r] / 11.313708498984761f + a;
          if (diag && j > q) v = -1e30f;
          sv[mi][ni][r] = v;
        }
    }
#pragma unroll
    for (int mi = 0; mi < 2; mi++)
#pragma unroll
      for (int r = 0; r < 4; r++) {
        float mx = sv[mi][0][r];
#pragma unroll
        for (int ni = 1; ni < 8; ni++) mx = fmaxf(mx, sv[mi][ni][r]);
#pragma unroll
        for (int o = 1; o < 16; o <<= 1) mx = fmaxf(mx, __shfl_xor(mx, o, 64));
        float nm = fmaxf(rm[mi][r], mx);
        float sum = 0.f;
#pragma unroll
        for (int ni = 0; ni < 8; ni++) sum += expf(sv[mi][ni][r] - nm);
#pragma unroll
        for (int o = 1; o < 16; o <<= 1) sum += __shfl_xor(sum, o, 64);
        rl[mi][r] = rl[mi][r] * expf(rm[mi][r] - nm) + sum;
        rm[mi][r] = nm;
      }
  }
  if (cc == 0) {
#pragma unroll
    for (int mi = 0; mi < 2; mi++)
#pragma unroll
      for (int r = 0; r < 4; r++) {
        int q = q0 + wave * 32 + mi * 16 + quad * 4 + r;
        m_g[h * S_LEN + q] = rm[mi][r];
        l_g[h * S_LEN + q] = rl[mi][r];
      }
  }
}

// -------------------------------------------------------------- flash pass 2
__global__ __launch_bounds__(256) void attn_pass2(
    const f16* __restrict__ Q1, const f16* __restrict__ Q2,
    const f16* __restrict__ K1g, const f16* __restrict__ K2g,
    const f16* __restrict__ Vt, const float* __restrict__ am,
    const float* __restrict__ m_g, const float* __restrict__ l_g,
    float* __restrict__ colsum, f16* __restrict__ attnb) {
  const int bx = (int)gridDim.x - 1 - (int)blockIdx.x, h = blockIdx.y;
  const int tid = threadIdx.x, wave = tid >> 6, lane = tid & 63;
  const int quad = lane >> 4, cc = lane & 15;
  const int q0 = bx * 128;
  __shared__ __attribute__((aligned(16))) f16 Kbuf[4][128][32];  // K1, then K2, then W
  __shared__ __attribute__((aligned(16))) f16 Vs[4][128][32];
  const f16* Qh1 = Q1 + (size_t)h * S_LEN * HSZ;
  const f16* Qh2 = Q2 + (size_t)h * S_LEN * HSZ;
  const f16* Kh1 = K1g + (size_t)h * S_LEN * HSZ;
  const f16* Kh2 = K2g + (size_t)h * S_LEN * HSZ;
  const f16* Vh = Vt + (size_t)h * HSZ * S_LEN;
  f16x8 qf1[2][4], qf2[2][4];
#pragma unroll
  for (int mi = 0; mi < 2; mi++)
#pragma unroll
    for (int kc = 0; kc < 4; kc++) {
      size_t off = (size_t)(q0 + wave * 32 + mi * 16 + cc) * HSZ + kc * 32 + quad * 8;
      qf1[mi][kc] = *(const f16x8*)(Qh1 + off);
      qf2[mi][kc] = *(const f16x8*)(Qh2 + off);
    }
  float rm[2][4], rl[2][4];
#pragma unroll
  for (int mi = 0; mi < 2; mi++)
#pragma unroll
    for (int r = 0; r < 4; r++) {
      int q = q0 + wave * 32 + mi * 16 + quad * 4 + r;
      rm[mi][r] = m_g[h * S_LEN + q];
      rl[mi][r] = l_g[h * S_LEN + q];
    }
  f32x4 oacc[2][8] = {};
  const int lrow = lane >> 2;
  const int lcs = (((lane & 3) ^ (lrow & 3)) * 8);
  const int sA = (quad ^ (cc & 3)) * 8;
  for (int jt = 0; jt <= bx; ++jt) {
    int j0 = jt * 128;
    __syncthreads();   // prior-iter PV reads done
#pragma unroll
    for (int ii = 0; ii < 8; ++ii) {
      async16(Kh1 + (size_t)(j0 + ii * 16 + lrow) * HSZ + wave * 32 + lcs, &Kbuf[wave][ii * 16][0]);
      async16(Vh + (size_t)(ii * 16 + lrow) * S_LEN + j0 + wave * 32 + lcs, &Vs[wave][ii * 16][0]);
    }
    __syncthreads();
    f32x4 sv[2][8] = {};
#pragma unroll
    for (int ni = 0; ni < 8; ni++)
#pragma unroll
      for (int kc = 0; kc < 4; kc++) {
        f16x8 b1 = *(const f16x8*)&Kbuf[kc][ni * 16 + cc][sA];
        sv[0][ni] = MFMA16(qf2[0][kc], b1, sv[0][ni], 0, 0, 0);
        sv[0][ni] = MFMA16(qf1[0][kc], b1, sv[0][ni], 0, 0, 0);
        sv[1][ni] = MFMA16(qf2[1][kc], b1, sv[1][ni], 0, 0, 0);
        sv[1][ni] = MFMA16(qf1[1][kc], b1, sv[1][ni], 0, 0, 0);
      }
    __syncthreads();   // all waves done reading K1
#pragma unroll
    for (int ii = 0; ii < 8; ++ii)
      async16(Kh2 + (size_t)(j0 + ii * 16 + lrow) * HSZ + wave * 32 + lcs, &Kbuf[wave][ii * 16][0]);
    __syncthreads();
#pragma unroll
    for (int ni = 0; ni < 8; ni++)
#pragma unroll
      for (int kc = 0; kc < 4; kc++) {
        f16x8 b2 = *(const f16x8*)&Kbuf[kc][ni * 16 + cc][sA];
        sv[0][ni] = MFMA16(qf1[0][kc], b2, sv[0][ni], 0, 0, 0);
        sv[1][ni] = MFMA16(qf1[1][kc], b2, sv[1][ni], 0, 0, 0);
      }
    bool diag = (jt == bx);
#pragma unroll
    for (int ni = 0; ni < 8; ni++) {
      int j = j0 + ni * 16 + cc;
      float a = am[j];
#pragma unroll
      for (int mi = 0; mi < 2; mi++)
#pragma unroll
        for (int r = 0; r < 4; r++) {
          int q = q0 + wave * 32 + mi * 16 + quad * 4 + r;
          float v = sv[mi][ni][r] / 11.313708498984761f + a;
          if (diag && j > q) v = -1e30f;
          sv[mi][ni][r] = expf(v - rm[mi][r]) / rl[mi][r];
        }
    }
#pragma unroll
    for (int ni = 0; ni < 8; ni++) {
      float p = 0.f;
#pragma unroll
      for (int mi = 0; mi < 2; mi++)
#pragma unroll
        for (int r = 0; r < 4; r++) p += sv[mi][ni][r];
      p += __shfl_xor(p, 16, 64);
      p += __shfl_xor(p, 32, 64);
      if (quad == 0) atomicAdd(&colsum[h * S_LEN + j0 + ni * 16 + cc], p);
    }
    __syncthreads();   // all waves done reading K2 before W overwrite
    // W element (q, j): row q_local, col ((jblk ^ (q&3))*8 + j%8); q&3 == r
#pragma unroll
    for (int ni = 0; ni < 8; ni++)
#pragma unroll
      for (int mi = 0; mi < 2; mi++)
#pragma unroll
        for (int r = 0; r < 4; r++) {
          int col = ((((ni & 1) * 2 + (cc >> 3)) ^ r) * 8) + (cc & 7);
          Kbuf[ni >> 1][wave * 32 + mi * 16 + quad * 4 + r][col] = (f16)sv[mi][ni][r];
        }
    // PV: each wave reads only its own 32 W rows
#pragma unroll
    for (int jc = 0; jc < 4; jc++) {
      f16x8 wf0 = *(const f16x8*)&Kbuf[jc][wave * 32 + cc][sA];
      f16x8 wf1 = *(const f16x8*)&Kbuf[jc][wave * 32 + 16 + cc][sA];
#pragma unroll
      for (int dn = 0; dn < 8; dn++) {
        f16x8 vf = *(const f16x8*)&Vs[jc][dn * 16 + cc][sA];
        oacc[0][dn] = MFMA16(wf0, vf, oacc[0][dn], 0, 0, 0);
        oacc[1][dn] = MFMA16(wf1, vf, oacc[1][dn], 0, 0, 0);
      }
    }
  }
#pragma unroll
  for (int mi = 0; mi < 2; mi++)
#pragma unroll
    for (int dn = 0; dn < 8; dn++)
#pragma unroll
      for (int r = 0; r < 4; r++) {
        int q = q0 + wave * 32 + mi * 16 + quad * 4 + r;
        attnb[(size_t)q * HID + h * HSZ + dn * 16 + cc] = (f16)oacc[mi][dn][r];
      }
}

// ------------------------------------------------------------- top-k -> mask
// Radix-select (4x8-bit, MSB first) of the 204th-largest key, then mark all
// strictly-greater + first k_rem equals by index (jax.lax.top_k tie rule).
__global__ void topk_mask_kernel(const float* __restrict__ colsum, float* __restrict__ outmask) {
  int h = blockIdx.x, t = threadIdx.x;
  __shared__ unsigned int keys[SEL_N];
  __shared__ int hist[256];
  __shared__ int sh_b, sh_acc, sh_gt;
  const float* cs = colsum + h * S_LEN;
  float* om = outmask + h * (S_LEN + 1);
  for (int i = t; i < SEL_N; i += 256) {
    unsigned int u = __float_as_uint(cs[i]);
    keys[i] = (u & 0x80000000u) ? ~u : (u | 0x80000000u);
  }
  for (int i = t; i < S_LEN + 1; i += 256) om[i] = (i >= S_LEN + 1 - RECENT) ? 1.f : 0.f;
  unsigned int pref = 0, pmask = 0;
  int k = HEAVY;
  for (int round = 0; round < 4; ++round) {
    int shift = 24 - 8 * round;
    if (t < 256) hist[t] = 0;
    __syncthreads();
    for (int i = t; i < SEL_N; i += 256) {
      unsigned int u = keys[i];
      if ((u & pmask) == pref) atomicAdd(&hist[(u >> shift) & 255], 1);
    }
    __syncthreads();
    if (t == 0) {
      int acc = 0, b = 255;
      for (; b > 0; --b) {
        int c = hist[b];
        if (acc + c >= k) break;
        acc += c;
      }
      sh_b = b; sh_acc = acc;
    }
    __syncthreads();
    k -= sh_acc;
    pref |= ((unsigned int)sh_b) << shift;
    pmask |= 0xFFu << shift;
    __syncthreads();
  }
  unsigned int T = pref;
  if (t == 0) sh_gt = 0;
  __syncthreads();
  for (int i = t; i < SEL_N; i += 256) {
    if (keys[i] > T) { om[i] = 1.0f; atomicAdd(&sh_gt, 1); }
  }
  __syncthreads();
  if (t == 0) {
    int krem = HEAVY - sh_gt;
    for (int i = 0; i < SEL_N && krem > 0; ++i)
      if (keys[i] == T) { om[i] = 1.0f; --krem; }
  }
}

// ------------------------------------------------------------------- launch
extern "C" void kernel_launch(void* const* d_in, const int* in_sizes, int n_in,
                              void* d_out, int out_size, void* d_ws, size_t ws_size,
                              hipStream_t stream) {
  const float* hs   = (const float*)d_in[0];
  const float* am   = (const float*)d_in[1];
  const int*   pos  = (const int*)d_in[2];
  const float* qkvw = (const float*)d_in[3];
  const float* qkvb = (const float*)d_in[4];
  const float* dw   = (const float*)d_in[5];
  const float* db   = (const float*)d_in[6];
  float* out = (float*)d_out;
  char* ws = (char*)d_ws;
  const size_t MB = 1048576;

  f16* H1 = (f16*)(ws);             // 16 MB
  f16* H2 = (f16*)(ws + 16 * MB);   // 16 MB
  f16* W1 = (f16*)(ws + 32 * MB);   // 64 MB  (dead after gemm3)
  f16* W2 = (f16*)(ws + 96 * MB);   // 64 MB  (dead after gemm3)
  f16* Wv = (f16*)(ws + 160 * MB);  // 32 MB
  f16* Wd = (f16*)(ws + 192 * MB);  // 32 MB
  float* QKm = (float*)(ws + 224 * MB);  // 64 MB
  float* Vm  = (float*)(ws + 288 * MB);  // 32 MB
  float* qkb = (float*)(ws + 320 * MB);
  float* vb  = (float*)(ws + 320 * MB + 65536);
  float* m_g = (float*)(ws + 321 * MB);
  float* l_g = (float*)(ws + 321 * MB + 262144);
  float* csum = (float*)(ws + 321 * MB + 524288);
  float2* tab = (float2*)(ws + 322 * MB);   // 256 KB; end ~322.25 MB
  // aliased into dead W1/W2 region after gemm3:
  f16* Q1 = (f16*)(ws + 32 * MB);
  f16* Q2 = (f16*)(ws + 48 * MB);
  f16* K1 = (f16*)(ws + 64 * MB);
  f16* K2 = (f16*)(ws + 80 * MB);
  f16* Vt = (f16*)(ws + 96 * MB);
  f16* attnb = (f16*)(ws + 112 * MB);

  rope_tab_kernel<<<128, 256, 0, stream>>>(pos, tab);
  cvt_split_h<<<8192, 256, 0, stream>>>(hs, H1, H2, 2097152);
  cvt_wqk<<<32768, 256, 0, stream>>>(qkvw, W1, W2);
  cvt_wv<<<16384, 256, 0, stream>>>(qkvw, Wv);
  cvt_wd<<<16384, 256, 0, stream>>>(dw, Wd);
  bias_perm<<<48, 256, 0, stream>>>(qkvb, qkb, vb);

  gemm3_f16<<<dim3(64, 16), 256, 0, stream>>>(H1, H2, W1, W2, qkb, QKm,
                                              2048, 8192, 4096, 1.0f / 4096.0f);
  gemm1_f16<<<dim3(32, 16), 256, 0, stream>>>(H1, Wv, vb, Vm,
                                              2048, 4096, 4096, 1.0f / 4096.0f);
  rope_split<<<32768, 256, 0, stream>>>(QKm, tab, Q1, Q2, K1, K2);
  v_transpose<<<dim3(16, 32), 256, 0, stream>>>(Vm, Vt);

  hipMemsetAsync(csum, 0, NHEAD * S_LEN * sizeof(float), stream);
  attn_pass1<<<dim3(16, 32), 256, 0, stream>>>(Q1, Q2, K1, K2, am, m_g, l_g);
  attn_pass2<<<dim3(16, 32), 256, 0, stream>>>(Q1, Q2, K1, K2, Vt, am, m_g, l_g, csum, attnb);

  gemm1_f16<<<dim3(32, 16), 256, 0, stream>>>(attnb, Wd, db, out,
                                              2048, 4096, 4096, 1.0f / 4096.0f);
  topk_mask_kernel<<<32, 256, 0, stream>>>(csum, out + 8388608);
}

// Round 4
// 1567.359 us; speedup vs baseline: 1.2538x; 1.2070x over previous
//
#include <hip/hip_runtime.h>
#include <cfloat>
#include <cstdint>
#include <cstddef>

// ---------------------------------------------------------------------------
// GPT-NeoX attention + H2O mask, MI355X. Rank-exact colsum path via fp16
// two-term splits and 3-product MFMA (error ~2^-22). R6: causal-triangle
// load balancing for both attention passes. Old dim3(16,32) grid paired
// same-bx blocks on each CU (block i and i+256 share a CU under round-robin
// dispatch; both had identical blockIdx.x -> identical work (bx+1)) ->
// worst CU did 32 tile-units vs mean 17 (Occupancy 6.9%, MfmaUtil 6.2%).
// New 1-D 512-block grid maps L -> (h, bx) with complement pairing:
// slot=L>>8, r=L&255, h=r>>3, i=r&7, bx = slot ? i : 15-i, so co-resident
// blocks do (16-i)+(i+1)=17 units. Per-block work unchanged -> bit-identical.
// gemm3 keeps the R5 6-slot counted-vmcnt schedule.
// ---------------------------------------------------------------------------

#define S_LEN 2048
#define HID 4096
#define NHEAD 32
#define HSZ 128
#define HEAVY 204
#define RECENT 204
#define SEL_N 1844   // S - RECENT

typedef _Float16 f16;
typedef __attribute__((ext_vector_type(4))) _Float16 f16x4;
typedef __attribute__((ext_vector_type(8))) _Float16 f16x8;
typedef __attribute__((ext_vector_type(4))) float f32x4;

#define MFMA16 __builtin_amdgcn_mfma_f32_16x16x32_f16

__device__ __forceinline__ void async16(const void* g, void* l) {
  __builtin_amdgcn_global_load_lds(
      (const __attribute__((address_space(1))) unsigned int*)g,
      (__attribute__((address_space(3))) unsigned int*)l, 16, 0, 0);
}

// ---------------------------------------------------------------- converters
__global__ void cvt_split_h(const float* __restrict__ in, f16* __restrict__ o1,
                            f16* __restrict__ o2, int n4) {
  int i = blockIdx.x * 256 + threadIdx.x;
  if (i >= n4) return;
  float4 v = ((const float4*)in)[i];
  float vv[4] = {v.x, v.y, v.z, v.w};
  f16x4 a, b;
#pragma unroll
  for (int j = 0; j < 4; j++) {
    f16 h = (f16)vv[j];
    a[j] = h;
    b[j] = (f16)(vv[j] - (float)h);
  }
  ((f16x4*)o1)[i] = a;
  ((f16x4*)o2)[i] = b;
}

__global__ void cvt_wqk(const float* __restrict__ w, f16* __restrict__ o1,
                        f16* __restrict__ o2) {
  int i = blockIdx.x * 256 + threadIdx.x;   // over 8192*1024 float4s
  int col4 = i & 1023, r = i >> 10;
  int c = (r >> 8) * 384 + (r & 255);
  float4 v = ((const float4*)(w + (size_t)c * HID))[col4];
  float vv[4] = {v.x * 4096.f, v.y * 4096.f, v.z * 4096.f, v.w * 4096.f};
  f16x4 a, b;
#pragma unroll
  for (int j = 0; j < 4; j++) {
    f16 h = (f16)vv[j];
    a[j] = h;
    b[j] = (f16)(vv[j] - (float)h);
  }
  ((f16x4*)o1)[(size_t)r * 1024 + col4] = a;
  ((f16x4*)o2)[(size_t)r * 1024 + col4] = b;
}

__global__ void cvt_wv(const float* __restrict__ w, f16* __restrict__ o1) {
  int i = blockIdx.x * 256 + threadIdx.x;   // over 4096*1024
  int col4 = i & 1023, r = i >> 10;
  int c = (r >> 7) * 384 + 256 + (r & 127);
  float4 v = ((const float4*)(w + (size_t)c * HID))[col4];
  f16x4 a;
  a[0] = (f16)(v.x * 4096.f); a[1] = (f16)(v.y * 4096.f);
  a[2] = (f16)(v.z * 4096.f); a[3] = (f16)(v.w * 4096.f);
  ((f16x4*)o1)[(size_t)r * 1024 + col4] = a;
}

__global__ void cvt_wd(const float* __restrict__ w, f16* __restrict__ o1) {
  int i = blockIdx.x * 256 + threadIdx.x;
  float4 v = ((const float4*)w)[i];
  f16x4 a;
  a[0] = (f16)(v.x * 4096.f); a[1] = (f16)(v.y * 4096.f);
  a[2] = (f16)(v.z * 4096.f); a[3] = (f16)(v.w * 4096.f);
  ((f16x4*)o1)[i] = a;
}

__global__ void bias_perm(const float* __restrict__ qkvb, float* __restrict__ qkb,
                          float* __restrict__ vb) {
  int t = blockIdx.x * 256 + threadIdx.x;
  if (t < 8192) qkb[t] = qkvb[(t >> 8) * 384 + (t & 255)];
  else if (t < 12288) {
    int i = t - 8192;
    vb[i] = qkvb[(i >> 7) * 384 + 256 + (i & 127)];
  }
}

// cos/sin table: the only fp64 trig in the pipeline (32k evals, not 2M)
__global__ void rope_tab_kernel(const int* __restrict__ pos, float2* __restrict__ tab) {
  int idx = blockIdx.x * 256 + threadIdx.x;
  if (idx >= S_LEN * 16) return;
  int s = idx >> 4, i = idx & 15;
  float pf = (float)pow(10000.0, (double)i / 16.0);  // RN32 of true power
  float invf = 1.0f / pf;                             // = np 1.0/p
  float ph = (float)pos[s] * invf;                    // fp32 phase
  double pd = (double)ph;
  tab[idx] = make_float2((float)cos(pd), (float)sin(pd));
}

// ------------------------------------------------------- gemm3 (fp32-exact)
// C = ((A1+A2)@(B1+B2)^T)*descale + bias; drops A2*B2 (~2^-22).
// Round-0 geometry; 6-slot counted-vmcnt schedule (see R5 header comment).
__global__ __launch_bounds__(256) void gemm3_f16(
    const f16* __restrict__ A1, const f16* __restrict__ A2,
    const f16* __restrict__ B1, const f16* __restrict__ B2,
    const float* __restrict__ bias, float* __restrict__ C,
    int M, int N, int K, float descale) {
  __shared__ __attribute__((aligned(16))) f16 B1s[2][128][32];
  __shared__ __attribute__((aligned(16))) f16 A2s[2][128][32];
  __shared__ __attribute__((aligned(16))) f16 A1s[128][32];
  __shared__ __attribute__((aligned(16))) f16 B2s[128][32];
  const int tid = threadIdx.x, wave = tid >> 6, lane = tid & 63;
  const int quad = lane >> 4, cc = lane & 15;
  const int m0 = blockIdx.y * 128, n0 = blockIdx.x * 128;
  const int wm = wave >> 1, wn = wave & 1;
  f32x4 acc[4][4] = {};
  const int lrow = lane >> 2;
  const int lcs = (((lane & 3) ^ (lrow & 3)) * 8);   // pre-swizzled src chunk
  const int sA = (quad ^ (cc & 3)) * 8;              // swizzled read seg
  const f16* A1g = A1 + (size_t)(m0 + wave * 32 + lrow) * K + lcs;
  const f16* A2g = A2 + (size_t)(m0 + wave * 32 + lrow) * K + lcs;
  const f16* B1g = B1 + (size_t)(n0 + wave * 32 + lrow) * K + lcs;
  const f16* B2g = B2 + (size_t)(n0 + wave * 32 + lrow) * K + lcs;
  const size_t RSTEP = (size_t)16 * K;
  const int nt = K >> 5;
  // prologue: group1(t=0) = {B1,A2}, then group2(t=0) = {A1,B2}
  async16(B1g, &B1s[0][wave * 32][0]);
  async16(B1g + RSTEP, &B1s[0][wave * 32 + 16][0]);
  async16(A2g, &A2s[0][wave * 32][0]);
  async16(A2g + RSTEP, &A2s[0][wave * 32 + 16][0]);
  async16(A1g, &A1s[wave * 32][0]);
  async16(A1g + RSTEP, &A1s[wave * 32 + 16][0]);
  async16(B2g, &B2s[wave * 32][0]);
  async16(B2g + RSTEP, &B2s[wave * 32 + 16][0]);
  f16x8 a1[4], b1[4];
  for (int t = 0; t < nt; ++t) {
    const int buf = t & 1, nb = buf ^ 1;
    const int kn = (t + 1 < nt) ? (t + 1) * 32 : 0;  // tail: harmless restage
    // ---- barrier A: need B1[t],A2[t] (oldest 4 of 8 outstanding) ---------
    asm volatile("s_waitcnt vmcnt(4)" ::: "memory");
    __builtin_amdgcn_s_barrier();
    __builtin_amdgcn_sched_barrier(0);
    async16(B1g + kn, &B1s[nb][wave * 32][0]);
    async16(B1g + RSTEP + kn, &B1s[nb][wave * 32 + 16][0]);
    async16(A2g + kn, &A2s[nb][wave * 32][0]);
    async16(A2g + RSTEP + kn, &A2s[nb][wave * 32 + 16][0]);
    // ---- phase A: acc += a2*b1 -------------------------------------------
#pragma unroll
    for (int ni = 0; ni < 4; ni++)
      b1[ni] = *(const f16x8*)&B1s[buf][wn * 64 + ni * 16 + cc][sA];
    __builtin_amdgcn_s_setprio(1);
#pragma unroll
    for (int mi = 0; mi < 4; mi++) {
      f16x8 a2 = *(const f16x8*)&A2s[buf][wm * 64 + mi * 16 + cc][sA];
#pragma unroll
      for (int ni = 0; ni < 4; ni++)
        acc[mi][ni] = MFMA16(a2, b1[ni], acc[mi][ni], 0, 0, 0);
    }
    __builtin_amdgcn_s_setprio(0);
    // ---- barrier B: need A1[t],B2[t] (oldest 4; B1/A2[t+1] younger) ------
    asm volatile("s_waitcnt vmcnt(4)" ::: "memory");
    __builtin_amdgcn_s_barrier();
    __builtin_amdgcn_sched_barrier(0);
    // ---- phase B: acc += a1*b2 -------------------------------------------
#pragma unroll
    for (int mi = 0; mi < 4; mi++)
      a1[mi] = *(const f16x8*)&A1s[wm * 64 + mi * 16 + cc][sA];
    __builtin_amdgcn_s_setprio(1);
#pragma unroll
    for (int ni = 0; ni < 4; ni++) {
      f16x8 b2 = *(const f16x8*)&B2s[wn * 64 + ni * 16 + cc][sA];
#pragma unroll
      for (int mi = 0; mi < 4; mi++)
        acc[mi][ni] = MFMA16(a1[mi], b2, acc[mi][ni], 0, 0, 0);
    }
    __builtin_amdgcn_s_setprio(0);
    // ---- barrier C: all waves done reading A1s/B2s -> safe to overwrite --
    __builtin_amdgcn_s_barrier();
    __builtin_amdgcn_sched_barrier(0);
    async16(A1g + kn, &A1s[wave * 32][0]);
    async16(A1g + RSTEP + kn, &A1s[wave * 32 + 16][0]);
    async16(B2g + kn, &B2s[wave * 32][0]);
    async16(B2g + RSTEP + kn, &B2s[wave * 32 + 16][0]);
    // ---- phase C: acc += a1*b1 (register-resident) -----------------------
    __builtin_amdgcn_s_setprio(1);
#pragma unroll
    for (int mi = 0; mi < 4; mi++)
#pragma unroll
      for (int ni = 0; ni < 4; ni++)
        acc[mi][ni] = MFMA16(a1[mi], b1[ni], acc[mi][ni], 0, 0, 0);
    __builtin_amdgcn_s_setprio(0);
  }
  asm volatile("s_waitcnt vmcnt(0)" ::: "memory");   // drain tail restage
#pragma unroll
  for (int mi = 0; mi < 4; mi++) {
    int row = m0 + wm * 64 + mi * 16 + quad * 4;
#pragma unroll
    for (int ni = 0; ni < 4; ni++) {
      int col = n0 + wn * 64 + ni * 16 + cc;
      float bs = bias[col];
#pragma unroll
      for (int r = 0; r < 4; r++)
        C[(size_t)(row + r) * N + col] = acc[mi][ni][r] * descale + bs;
    }
  }
}

// -------------------------------------------------- gemm1 (loose-precision)
__global__ __launch_bounds__(256) void gemm1_f16(
    const f16* __restrict__ A, const f16* __restrict__ B,
    const float* __restrict__ bias, float* __restrict__ C,
    int M, int N, int K, float descale) {
  __shared__ __attribute__((aligned(16))) f16 As[128][32];
  __shared__ __attribute__((aligned(16))) f16 Bs[128][32];
  const int tid = threadIdx.x, wave = tid >> 6, lane = tid & 63;
  const int quad = lane >> 4, cc = lane & 15;
  const int m0 = blockIdx.y * 128, n0 = blockIdx.x * 128;
  const int wm = wave >> 1, wn = wave & 1;
  f32x4 acc[4][4] = {};
  const int lrow = lane >> 2;
  const int lcs = (((lane & 3) ^ (lrow & 3)) * 8);
  const int sA = (quad ^ (cc & 3)) * 8;
  const f16* Ag = A + (size_t)(m0 + wave * 32 + lrow) * K + lcs;
  const f16* Bg = B + (size_t)(n0 + wave * 32 + lrow) * K + lcs;
  for (int k0 = 0; k0 < K; k0 += 32) {
    __syncthreads();
    async16(Ag + k0, &As[wave * 32][0]);
    async16(Ag + (size_t)16 * K + k0, &As[wave * 32 + 16][0]);
    async16(Bg + k0, &Bs[wave * 32][0]);
    async16(Bg + (size_t)16 * K + k0, &Bs[wave * 32 + 16][0]);
    __syncthreads();
    f16x8 af[4], bfv[4];
#pragma unroll
    for (int mi = 0; mi < 4; mi++) af[mi] = *(const f16x8*)&As[wm * 64 + mi * 16 + cc][sA];
#pragma unroll
    for (int ni = 0; ni < 4; ni++) bfv[ni] = *(const f16x8*)&Bs[wn * 64 + ni * 16 + cc][sA];
#pragma unroll
    for (int mi = 0; mi < 4; mi++)
#pragma unroll
      for (int ni = 0; ni < 4; ni++)
        acc[mi][ni] = MFMA16(af[mi], bfv[ni], acc[mi][ni], 0, 0, 0);
  }
#pragma unroll
  for (int mi = 0; mi < 4; mi++) {
    int row = m0 + wm * 64 + mi * 16 + quad * 4;
#pragma unroll
    for (int ni = 0; ni < 4; ni++) {
      int col = n0 + wn * 64 + ni * 16 + cc;
      float bs = bias[col];
#pragma unroll
      for (int r = 0; r < 4; r++)
        C[(size_t)(row + r) * N + col] = acc[mi][ni][r] * descale + bs;
    }
  }
}

// ---------------------------------------------------------------- RoPE/split
__global__ void rope_split(const float* __restrict__ QKm, const float2* __restrict__ tab,
                           f16* __restrict__ Q1, f16* __restrict__ Q2,
                           f16* __restrict__ K1, f16* __restrict__ K2) {
  int idx = blockIdx.x * 256 + threadIdx.x;
  int d = idx & 127;
  int s = (idx >> 7) & 2047;
  int h = idx >> 18;
  const float* base = QKm + (size_t)s * 8192 + h * 256;
  float q = base[d], k = base[128 + d];
  if (d < 32) {
    int i = d & 15;
    float2 csn = tab[s * 16 + i];
    float cs = csn.x, sn = csn.y;
    int dp = (d < 16) ? d + 16 : d - 16;
    float qp = base[dp], kp = base[128 + dp];
    if (d < 16) { q = q * cs - qp * sn; k = k * cs - kp * sn; }
    else        { q = q * cs + qp * sn; k = k * cs + kp * sn; }
  }
  size_t o = (size_t)h * S_LEN * HSZ + (size_t)s * HSZ + d;
  f16 a = (f16)q; Q1[o] = a; Q2[o] = (f16)(q - (float)a);
  f16 b = (f16)k; K1[o] = b; K2[o] = (f16)(k - (float)b);
}

__global__ void v_transpose(const float* __restrict__ Vm, f16* __restrict__ Vt) {
  int h = blockIdx.y, s0 = blockIdx.x * 128;
  __shared__ f16 tile[128][130];
  int t = threadIdx.x;
#pragma unroll 4
  for (int it = 0; it < 64; ++it) {
    int lin = it * 256 + t;
    int d = lin & 127, sl = lin >> 7;
    tile[d][sl] = (f16)Vm[(size_t)(s0 + sl) * HID + h * HSZ + d];
  }
  __syncthreads();
#pragma unroll 4
  for (int it = 0; it < 64; ++it) {
    int lin = it * 256 + t;
    int sl = lin & 127, d = lin >> 7;
    Vt[(size_t)h * HSZ * S_LEN + (size_t)d * S_LEN + s0 + sl] = tile[d][sl];
  }
}

// -------------------------------------------------------------- flash pass 1
// Single-stage K1+K2 (64 KB LDS, 2 barriers/tile). Product order per sv:
// kc0..3 of (q2k1,q1k1), then kc0..3 of q1k2 — identical to pass2.
// Grid: 512 blocks, complement-paired (h, bx) mapping for CU load balance.
__global__ __launch_bounds__(256) void attn_pass1(
    const f16* __restrict__ Q1, const f16* __restrict__ Q2,
    const f16* __restrict__ K1g, const f16* __restrict__ K2g,
    const float* __restrict__ am, float* __restrict__ m_g, float* __restrict__ l_g) {
  const int L = (int)blockIdx.x;          // 0..511
  const int slot = L >> 8, rr = L & 255;
  const int h = rr >> 3, iw = rr & 7;
  const int bx = slot ? iw : 15 - iw;     // heavy half first, complement second
  const int tid = threadIdx.x, wave = tid >> 6, lane = tid & 63;
  const int quad = lane >> 4, cc = lane & 15;
  const int q0 = bx * 128;
  __shared__ __attribute__((aligned(16))) f16 K1s[4][128][32];
  __shared__ __attribute__((aligned(16))) f16 K2s[4][128][32];
  const f16* Qh1 = Q1 + (size_t)h * S_LEN * HSZ;
  const f16* Qh2 = Q2 + (size_t)h * S_LEN * HSZ;
  const f16* Kh1 = K1g + (size_t)h * S_LEN * HSZ;
  const f16* Kh2 = K2g + (size_t)h * S_LEN * HSZ;
  f16x8 qf1[2][4], qf2[2][4];
#pragma unroll
  for (int mi = 0; mi < 2; mi++)
#pragma unroll
    for (int kc = 0; kc < 4; kc++) {
      size_t off = (size_t)(q0 + wave * 32 + mi * 16 + cc) * HSZ + kc * 32 + quad * 8;
      qf1[mi][kc] = *(const f16x8*)(Qh1 + off);
      qf2[mi][kc] = *(const f16x8*)(Qh2 + off);
    }
  float rm[2][4], rl[2][4];
#pragma unroll
  for (int mi = 0; mi < 2; mi++)
#pragma unroll
    for (int r = 0; r < 4; r++) { rm[mi][r] = -1e30f; rl[mi][r] = 0.f; }
  const int lrow = lane >> 2;
  const int lcs = (((lane & 3) ^ (lrow & 3)) * 8);
  const int sA = (quad ^ (cc & 3)) * 8;
  for (int jt = 0; jt <= bx; ++jt) {
    int j0 = jt * 128;
    __syncthreads();
#pragma unroll
    for (int ii = 0; ii < 8; ++ii) {
      async16(Kh1 + (size_t)(j0 + ii * 16 + lrow) * HSZ + wave * 32 + lcs, &K1s[wave][ii * 16][0]);
      async16(Kh2 + (size_t)(j0 + ii * 16 + lrow) * HSZ + wave * 32 + lcs, &K2s[wave][ii * 16][0]);
    }
    __syncthreads();
    f32x4 sv[2][8] = {};
#pragma unroll
    for (int ni = 0; ni < 8; ni++)
#pragma unroll
      for (int kc = 0; kc < 4; kc++) {
        f16x8 b1 = *(const f16x8*)&K1s[kc][ni * 16 + cc][sA];
        sv[0][ni] = MFMA16(qf2[0][kc], b1, sv[0][ni], 0, 0, 0);
        sv[0][ni] = MFMA16(qf1[0][kc], b1, sv[0][ni], 0, 0, 0);
        sv[1][ni] = MFMA16(qf2[1][kc], b1, sv[1][ni], 0, 0, 0);
        sv[1][ni] = MFMA16(qf1[1][kc], b1, sv[1][ni], 0, 0, 0);
      }
#pragma unroll
    for (int ni = 0; ni < 8; ni++)
#pragma unroll
      for (int kc = 0; kc < 4; kc++) {
        f16x8 b2 = *(const f16x8*)&K2s[kc][ni * 16 + cc][sA];
        sv[0][ni] = MFMA16(qf1[0][kc], b2, sv[0][ni], 0, 0, 0);
        sv[1][ni] = MFMA16(qf1[1][kc], b2, sv[1][ni], 0, 0, 0);
      }
    bool diag = (jt == bx);
#pragma unroll
    for (int ni = 0; ni < 8; ni++) {
      int j = j0 + ni * 16 + cc;
      float a = am[j];
#pragma unroll
      for (int mi = 0; mi < 2; mi++)
#pragma unroll
        for (int r = 0; r < 4; r++) {
          int q = q0 + wave * 32 + mi * 16 + quad * 4 + r;
          float v = sv[mi][ni][r] / 11.313708498984761f + a;
          if (diag && j > q) v = -1e30f;
          sv[mi][ni][r] = v;
        }
    }
#pragma unroll
    for (int mi = 0; mi < 2; mi++)
#pragma unroll
      for (int r = 0; r < 4; r++) {
        float mx = sv[mi][0][r];
#pragma unroll
        for (int ni = 1; ni < 8; ni++) mx = fmaxf(mx, sv[mi][ni][r]);
#pragma unroll
        for (int o = 1; o < 16; o <<= 1) mx = fmaxf(mx, __shfl_xor(mx, o, 64));
        float nm = fmaxf(rm[mi][r], mx);
        float sum = 0.f;
#pragma unroll
        for (int ni = 0; ni < 8; ni++) sum += expf(sv[mi][ni][r] - nm);
#pragma unroll
        for (int o = 1; o < 16; o <<= 1) sum += __shfl_xor(sum, o, 64);
        rl[mi][r] = rl[mi][r] * expf(rm[mi][r] - nm) + sum;
        rm[mi][r] = nm;
      }
  }
  if (cc == 0) {
#pragma unroll
    for (int mi = 0; mi < 2; mi++)
#pragma unroll
      for (int r = 0; r < 4; r++) {
        int q = q0 + wave * 32 + mi * 16 + quad * 4 + r;
        m_g[h * S_LEN + q] = rm[mi][r];
        l_g[h * S_LEN + q] = rl[mi][r];
      }
  }
}

// -------------------------------------------------------------- flash pass 2
// Grid: 512 blocks, complement-paired (h, bx) mapping for CU load balance.
__global__ __launch_bounds__(256) void attn_pass2(
    const f16* __restrict__ Q1, const f16* __restrict__ Q2,
    const f16* __restrict__ K1g, const f16* __restrict__ K2g,
    const f16* __restrict__ Vt, const float* __restrict__ am,
    const float* __restrict__ m_g, const float* __restrict__ l_g,
    float* __restrict__ colsum, f16* __restrict__ attnb) {
  const int L = (int)blockIdx.x;          // 0..511
  const int slot = L >> 8, rr = L & 255;
  const int h = rr >> 3, iw = rr & 7;
  const int bx = slot ? iw : 15 - iw;     // heavy half first, complement second
  const int tid = threadIdx.x, wave = tid >> 6, lane = tid & 63;
  const int quad = lane >> 4, cc = lane & 15;
  const int q0 = bx * 128;
  __shared__ __attribute__((aligned(16))) f16 Kbuf[4][128][32];  // K1, then K2, then W
  __shared__ __attribute__((aligned(16))) f16 Vs[4][128][32];
  const f16* Qh1 = Q1 + (size_t)h * S_LEN * HSZ;
  const f16* Qh2 = Q2 + (size_t)h * S_LEN * HSZ;
  const f16* Kh1 = K1g + (size_t)h * S_LEN * HSZ;
  const f16* Kh2 = K2g + (size_t)h * S_LEN * HSZ;
  const f16* Vh = Vt + (size_t)h * HSZ * S_LEN;
  f16x8 qf1[2][4], qf2[2][4];
#pragma unroll
  for (int mi = 0; mi < 2; mi++)
#pragma unroll
    for (int kc = 0; kc < 4; kc++) {
      size_t off = (size_t)(q0 + wave * 32 + mi * 16 + cc) * HSZ + kc * 32 + quad * 8;
      qf1[mi][kc] = *(const f16x8*)(Qh1 + off);
      qf2[mi][kc] = *(const f16x8*)(Qh2 + off);
    }
  float rm[2][4], rl[2][4];
#pragma unroll
  for (int mi = 0; mi < 2; mi++)
#pragma unroll
    for (int r = 0; r < 4; r++) {
      int q = q0 + wave * 32 + mi * 16 + quad * 4 + r;
      rm[mi][r] = m_g[h * S_LEN + q];
      rl[mi][r] = l_g[h * S_LEN + q];
    }
  f32x4 oacc[2][8] = {};
  const int lrow = lane >> 2;
  const int lcs = (((lane & 3) ^ (lrow & 3)) * 8);
  const int sA = (quad ^ (cc & 3)) * 8;
  for (int jt = 0; jt <= bx; ++jt) {
    int j0 = jt * 128;
    __syncthreads();   // prior-iter PV reads done
#pragma unroll
    for (int ii = 0; ii < 8; ++ii) {
      async16(Kh1 + (size_t)(j0 + ii * 16 + lrow) * HSZ + wave * 32 + lcs, &Kbuf[wave][ii * 16][0]);
      async16(Vh + (size_t)(ii * 16 + lrow) * S_LEN + j0 + wave * 32 + lcs, &Vs[wave][ii * 16][0]);
    }
    __syncthreads();
    f32x4 sv[2][8] = {};
#pragma unroll
    for (int ni = 0; ni < 8; ni++)
#pragma unroll
      for (int kc = 0; kc < 4; kc++) {
        f16x8 b1 = *(const f16x8*)&Kbuf[kc][ni * 16 + cc][sA];
        sv[0][ni] = MFMA16(qf2[0][kc], b1, sv[0][ni], 0, 0, 0);
        sv[0][ni] = MFMA16(qf1[0][kc], b1, sv[0][ni], 0, 0, 0);
        sv[1][ni] = MFMA16(qf2[1][kc], b1, sv[1][ni], 0, 0, 0);
        sv[1][ni] = MFMA16(qf1[1][kc], b1, sv[1][ni], 0, 0, 0);
      }
    __syncthreads();   // all waves done reading K1
#pragma unroll
    for (int ii = 0; ii < 8; ++ii)
      async16(Kh2 + (size_t)(j0 + ii * 16 + lrow) * HSZ + wave * 32 + lcs, &Kbuf[wave][ii * 16][0]);
    __syncthreads();
#pragma unroll
    for (int ni = 0; ni < 8; ni++)
#pragma unroll
      for (int kc = 0; kc < 4; kc++) {
        f16x8 b2 = *(const f16x8*)&Kbuf[kc][ni * 16 + cc][sA];
        sv[0][ni] = MFMA16(qf1[0][kc], b2, sv[0][ni], 0, 0, 0);
        sv[1][ni] = MFMA16(qf1[1][kc], b2, sv[1][ni], 0, 0, 0);
      }
    bool diag = (jt == bx);
#pragma unroll
    for (int ni = 0; ni < 8; ni++) {
      int j = j0 + ni * 16 + cc;
      float a = am[j];
#pragma unroll
      for (int mi = 0; mi < 2; mi++)
#pragma unroll
        for (int r = 0; r < 4; r++) {
          int q = q0 + wave * 32 + mi * 16 + quad * 4 + r;
          float v = sv[mi][ni][r] / 11.313708498984761f + a;
          if (diag && j > q) v = -1e30f;
          sv[mi][ni][r] = expf(v - rm[mi][r]) / rl[mi][r];
        }
    }
#pragma unroll
    for (int ni = 0; ni < 8; ni++) {
      float p = 0.f;
#pragma unroll
      for (int mi = 0; mi < 2; mi++)
#pragma unroll
        for (int r = 0; r < 4; r++) p += sv[mi][ni][r];
      p += __shfl_xor(p, 16, 64);
      p += __shfl_xor(p, 32, 64);
      if (quad == 0) atomicAdd(&colsum[h * S_LEN + j0 + ni * 16 + cc], p);
    }
    __syncthreads();   // all waves done reading K2 before W overwrite
    // W element (q, j): row q_local, col ((jblk ^ (q&3))*8 + j%8); q&3 == r
#pragma unroll
    for (int ni = 0; ni < 8; ni++)
#pragma unroll
      for (int mi = 0; mi < 2; mi++)
#pragma unroll
        for (int r = 0; r < 4; r++) {
          int col = ((((ni & 1) * 2 + (cc >> 3)) ^ r) * 8) + (cc & 7);
          Kbuf[ni >> 1][wave * 32 + mi * 16 + quad * 4 + r][col] = (f16)sv[mi][ni][r];
        }
    // PV: each wave reads only its own 32 W rows
#pragma unroll
    for (int jc = 0; jc < 4; jc++) {
      f16x8 wf0 = *(const f16x8*)&Kbuf[jc][wave * 32 + cc][sA];
      f16x8 wf1 = *(const f16x8*)&Kbuf[jc][wave * 32 + 16 + cc][sA];
#pragma unroll
      for (int dn = 0; dn < 8; dn++) {
        f16x8 vf = *(const f16x8*)&Vs[jc][dn * 16 + cc][sA];
        oacc[0][dn] = MFMA16(wf0, vf, oacc[0][dn], 0, 0, 0);
        oacc[1][dn] = MFMA16(wf1, vf, oacc[1][dn], 0, 0, 0);
      }
    }
  }
#pragma unroll
  for (int mi = 0; mi < 2; mi++)
#pragma unroll
    for (int dn = 0; dn < 8; dn++)
#pragma unroll
      for (int r = 0; r < 4; r++) {
        int q = q0 + wave * 32 + mi * 16 + quad * 4 + r;
        attnb[(size_t)q * HID + h * HSZ + dn * 16 + cc] = (f16)oacc[mi][dn][r];
      }
}

// ------------------------------------------------------------- top-k -> mask
// Radix-select (4x8-bit, MSB first) of the 204th-largest key, then mark all
// strictly-greater + first k_rem equals by index (jax.lax.top_k tie rule).
__global__ void topk_mask_kernel(const float* __restrict__ colsum, float* __restrict__ outmask) {
  int h = blockIdx.x, t = threadIdx.x;
  __shared__ unsigned int keys[SEL_N];
  __shared__ int hist[256];
  __shared__ int sh_b, sh_acc, sh_gt;
  const float* cs = colsum + h * S_LEN;
  float* om = outmask + h * (S_LEN + 1);
  for (int i = t; i < SEL_N; i += 256) {
    unsigned int u = __float_as_uint(cs[i]);
    keys[i] = (u & 0x80000000u) ? ~u : (u | 0x80000000u);
  }
  for (int i = t; i < S_LEN + 1; i += 256) om[i] = (i >= S_LEN + 1 - RECENT) ? 1.f : 0.f;
  unsigned int pref = 0, pmask = 0;
  int k = HEAVY;
  for (int round = 0; round < 4; ++round) {
    int shift = 24 - 8 * round;
    if (t < 256) hist[t] = 0;
    __syncthreads();
    for (int i = t; i < SEL_N; i += 256) {
      unsigned int u = keys[i];
      if ((u & pmask) == pref) atomicAdd(&hist[(u >> shift) & 255], 1);
    }
    __syncthreads();
    if (t == 0) {
      int acc = 0, b = 255;
      for (; b > 0; --b) {
        int c = hist[b];
        if (acc + c >= k) break;
        acc += c;
      }
      sh_b = b; sh_acc = acc;
    }
    __syncthreads();
    k -= sh_acc;
    pref |= ((unsigned int)sh_b) << shift;
    pmask |= 0xFFu << shift;
    __syncthreads();
  }
  unsigned int T = pref;
  if (t == 0) sh_gt = 0;
  __syncthreads();
  for (int i = t; i < SEL_N; i += 256) {
    if (keys[i] > T) { om[i] = 1.0f; atomicAdd(&sh_gt, 1); }
  }
  __syncthreads();
  if (t == 0) {
    int krem = HEAVY - sh_gt;
    for (int i = 0; i < SEL_N && krem > 0; ++i)
      if (keys[i] == T) { om[i] = 1.0f; --krem; }
  }
}

// ------------------------------------------------------------------- launch
extern "C" void kernel_launch(void* const* d_in, const int* in_sizes, int n_in,
                              void* d_out, int out_size, void* d_ws, size_t ws_size,
                              hipStream_t stream) {
  const float* hs   = (const float*)d_in[0];
  const float* am   = (const float*)d_in[1];
  const int*   pos  = (const int*)d_in[2];
  const float* qkvw = (const float*)d_in[3];
  const float* qkvb = (const float*)d_in[4];
  const float* dw   = (const float*)d_in[5];
  const float* db   = (const float*)d_in[6];
  float* out = (float*)d_out;
  char* ws = (char*)d_ws;
  const size_t MB = 1048576;

  f16* H1 = (f16*)(ws);             // 16 MB
  f16* H2 = (f16*)(ws + 16 * MB);   // 16 MB
  f16* W1 = (f16*)(ws + 32 * MB);   // 64 MB  (dead after gemm3)
  f16* W2 = (f16*)(ws + 96 * MB);   // 64 MB  (dead after gemm3)
  f16* Wv = (f16*)(ws + 160 * MB);  // 32 MB
  f16* Wd = (f16*)(ws + 192 * MB);  // 32 MB
  float* QKm = (float*)(ws + 224 * MB);  // 64 MB
  float* Vm  = (float*)(ws + 288 * MB);  // 32 MB
  float* qkb = (float*)(ws + 320 * MB);
  float* vb  = (float*)(ws + 320 * MB + 65536);
  float* m_g = (float*)(ws + 321 * MB);
  float* l_g = (float*)(ws + 321 * MB + 262144);
  float* csum = (float*)(ws + 321 * MB + 524288);
  float2* tab = (float2*)(ws + 322 * MB);   // 256 KB; end ~322.25 MB
  // aliased into dead W1/W2 region after gemm3:
  f16* Q1 = (f16*)(ws + 32 * MB);
  f16* Q2 = (f16*)(ws + 48 * MB);
  f16* K1 = (f16*)(ws + 64 * MB);
  f16* K2 = (f16*)(ws + 80 * MB);
  f16* Vt = (f16*)(ws + 96 * MB);
  f16* attnb = (f16*)(ws + 112 * MB);

  rope_tab_kernel<<<128, 256, 0, stream>>>(pos, tab);
  cvt_split_h<<<8192, 256, 0, stream>>>(hs, H1, H2, 2097152);
  cvt_wqk<<<32768, 256, 0, stream>>>(qkvw, W1, W2);
  cvt_wv<<<16384, 256, 0, stream>>>(qkvw, Wv);
  cvt_wd<<<16384, 256, 0, stream>>>(dw, Wd);
  bias_perm<<<48, 256, 0, stream>>>(qkvb, qkb, vb);

  gemm3_f16<<<dim3(64, 16), 256, 0, stream>>>(H1, H2, W1, W2, qkb, QKm,
                                              2048, 8192, 4096, 1.0f / 4096.0f);
  gemm1_f16<<<dim3(32, 16), 256, 0, stream>>>(H1, Wv, vb, Vm,
                                              2048, 4096, 4096, 1.0f / 4096.0f);
  rope_split<<<32768, 256, 0, stream>>>(QKm, tab, Q1, Q2, K1, K2);
  v_transpose<<<dim3(16, 32), 256, 0, stream>>>(Vm, Vt);

  hipMemsetAsync(csum, 0, NHEAD * S_LEN * sizeof(float), stream);
  attn_pass1<<<dim3(512), 256, 0, stream>>>(Q1, Q2, K1, K2, am, m_g, l_g);
  attn_pass2<<<dim3(512), 256, 0, stream>>>(Q1, Q2, K1, K2, Vt, am, m_g, l_g, csum, attnb);

  gemm1_f16<<<dim3(32, 16), 256, 0, stream>>>(attnb, Wd, db, out,
                                              2048, 4096, 4096, 1.0f / 4096.0f);
  topk_mask_kernel<<<32, 256, 0, stream>>>(csum, out + 8388608);
}